// Round 4
// baseline (11211.598 us; speedup 1.0000x reference)
//
#include <hip/hip_runtime.h>
#include <math.h>

#define NN    325
#define BB    64
#define TT    12
#define NODE  4096          // per-node stride of fp32 h buffers: [n][c<64][b<64]
#define KD    352           // padded node dim, 11*32
#define NPADR 384           // padded S rows (24 M-tiles of 16)
#define XP    360           // LDS pitch (nodes) for diff
#define KH    320           // wg K-chunk
#define NBLK  256           // persistent grid (1 block/CU guaranteed: LDS < 64KB)

typedef __attribute__((ext_vector_type(8))) short short8v;
typedef __attribute__((ext_vector_type(4))) short short4v;
typedef __attribute__((ext_vector_type(4))) float float4v;

static __device__ __forceinline__ unsigned short f2bf(float f){
  unsigned u = __builtin_bit_cast(unsigned, f);
  u += 0x7fffu + ((u >> 16) & 1u);          // RNE
  return (unsigned short)(u >> 16);
}
static __device__ __forceinline__ float bf2f(unsigned short h){
  unsigned u = ((unsigned)h) << 16;
  return __builtin_bit_cast(float, u);
}

struct Args {
  const float *inp, *init, *adj;
  const float *Wg0, *bg0, *Wc0, *bc0, *Wg1, *bg1, *Wc1, *bc1, *Wfc, *bfc;
  unsigned short *Sb, *Wg0t, *Wc0t, *Wg1t, *Wc1t, *matsL0, *matsL1;
  float *rs, *cs, *inpT, *h0, *h1, *rh, *uu, *out;
  int *bar;                                  // [0]=cnt, [1]=gen (memset 0 per call)
};

// ------------------------------------------- device-scope grid barrier ----
static __device__ __forceinline__ void gbar(int* bar, int& lg){
  __syncthreads();
  if (threadIdx.x == 0){
    ++lg;
    __threadfence();
    if (__hip_atomic_fetch_add(&bar[0], 1, __ATOMIC_ACQ_REL, __HIP_MEMORY_SCOPE_AGENT) == NBLK - 1){
      __hip_atomic_store(&bar[0], 0, __ATOMIC_RELAXED, __HIP_MEMORY_SCOPE_AGENT);
      __hip_atomic_store(&bar[1], lg, __ATOMIC_RELEASE, __HIP_MEMORY_SCOPE_AGENT);
    } else {
      while (__hip_atomic_load(&bar[1], __ATOMIC_ACQUIRE, __HIP_MEMORY_SCOPE_AGENT) < lg)
        __builtin_amdgcn_s_sleep(1);
    }
    __threadfence();
  }
  __syncthreads();
}

// ------------------------------------------------------ diff MFMA sweep ----
static __device__ __forceinline__ void diff_mm(
    const unsigned short* __restrict__ S, unsigned short (*X)[XP],
    float4v (&acc)[6][4], int w, int r, int g)
{
  #pragma unroll
  for (int i = 0; i < 6; ++i)
    #pragma unroll
    for (int j = 0; j < 4; ++j) acc[i][j] = (float4v){0.f,0.f,0.f,0.f};
  for (int kc = 0; kc < KD/32; ++kc){
    short8v a[6], bb[4];
    #pragma unroll
    for (int mt = 0; mt < 6; ++mt){
      int row = (w*6 + mt)*16 + r;
      a[mt] = *(const short8v*)&S[(size_t)row*KD + kc*32 + g*8];
    }
    #pragma unroll
    for (int nt = 0; nt < 4; ++nt)
      bb[nt] = *(const short8v*)&X[nt*16 + r][kc*32 + g*8];
    #pragma unroll
    for (int mt = 0; mt < 6; ++mt)
      #pragma unroll
      for (int nt = 0; nt < 4; ++nt)
        acc[mt][nt] = __builtin_amdgcn_mfma_f32_16x16x32_bf16(a[mt], bb[nt], acc[mt][nt], 0, 0, 0);
  }
}

// diffusion phase: units = 2 supports x nch channels, grid-strided.
static __device__ void diff_phase(
    const unsigned short* __restrict__ Sb, const float* __restrict__ srcA, int strideA,
    int csplit, const float* __restrict__ srcB, unsigned short* __restrict__ mats,
    int C, int Kpad, int cbase, int nch, unsigned short* smem)
{
  unsigned short (*X)[XP] = (unsigned short (*)[XP])smem;
  int t = threadIdx.x;
  int b = t & 63, w = t >> 6;
  int r = t & 15, g = (t >> 4) & 3;

  for (int u = blockIdx.x; u < 2*nch; u += NBLK){
    int c = cbase + (u % nch);
    int s = u / nch;
    const unsigned short* S = Sb + (size_t)s * NPADR * KD;
    __syncthreads();                        // prev unit's X reads done
    // stage x0 transposed into X (+ mats m=0 when s==0)
    for (int o8 = w; o8 < KD/8; o8 += 4){
      int n0 = o8*8;
      short8v pk;
      #pragma unroll
      for (int i = 0; i < 8; ++i){
        int n = n0 + i;
        float v = 0.f;
        if (n < NN)
          v = (c < csplit) ? srcA[(size_t)n*strideA + c*64 + b]
                           : srcB[(size_t)n*NODE + (c - csplit)*64 + b];
        pk[i] = (short)f2bf(v);
      }
      *(short8v*)&X[b][n0] = pk;
      if (s == 0){
        #pragma unroll
        for (int i = 0; i < 8; ++i){
          int n = n0 + i;
          if (n < NN) mats[((size_t)n*Kpad + c)*64 + b] = (unsigned short)pk[i];
        }
      }
    }
    __syncthreads();
    // x0 correction fragments -> registers (same coords as pass-2 output frags)
    short4v x0c[6][4];
    #pragma unroll
    for (int mt = 0; mt < 6; ++mt)
      #pragma unroll
      for (int nt = 0; nt < 4; ++nt) x0c[mt][nt] = (short4v){0,0,0,0};
    #pragma unroll
    for (int mt = 0; mt < 6; ++mt){
      int node0 = (w*6 + mt)*16 + g*4;
      if (node0 >= KD) continue;
      #pragma unroll
      for (int nt = 0; nt < 4; ++nt)
        x0c[mt][nt] = *(short4v*)&X[nt*16 + r][node0];
    }
    // pass 1: x1 = S @ x0
    float4v acc[6][4];
    diff_mm(S, X, acc, w, r, g);
    __syncthreads();                        // all pass-1 X reads done
    #pragma unroll
    for (int mt = 0; mt < 6; ++mt){
      int node0 = (w*6 + mt)*16 + g*4;
      if (node0 >= KD) continue;
      #pragma unroll
      for (int nt = 0; nt < 4; ++nt){
        int col = nt*16 + r;
        short4v pk;
        #pragma unroll
        for (int i = 0; i < 4; ++i) pk[i] = (short)f2bf(acc[mt][nt][i]);
        *(short4v*)&X[col][node0] = pk;     // x1 overwrites X in place
        #pragma unroll
        for (int i = 0; i < 4; ++i){
          int n = node0 + i;
          if (n < NN)
            mats[((size_t)n*Kpad + (1 + 2*s)*C + c)*64 + col] = (unsigned short)pk[i];
        }
      }
    }
    __syncthreads();
    // pass 2: x2 = 2*S@x1 - x0
    diff_mm(S, X, acc, w, r, g);
    #pragma unroll
    for (int mt = 0; mt < 6; ++mt){
      int node0 = (w*6 + mt)*16 + g*4;
      if (node0 >= KD) continue;
      #pragma unroll
      for (int nt = 0; nt < 4; ++nt){
        int col = nt*16 + r;
        #pragma unroll
        for (int i = 0; i < 4; ++i){
          int n = node0 + i;
          if (n < NN){
            float v = 2.f*acc[mt][nt][i] - bf2f((unsigned short)x0c[mt][nt][i]);
            mats[((size_t)n*Kpad + (2 + 2*s)*C + c)*64 + col] = f2bf(v);
          }
        }
      }
    }
  }
}

// ------------------------------------------------------- W-GEMM (MFMA) ----
template<int KPAD, int MODE, bool FC>
static __device__ void wg_phase(
    const unsigned short* __restrict__ mats, const unsigned short* __restrict__ Wt,
    const float* __restrict__ bias, float* __restrict__ h,
    float* __restrict__ rh, float* __restrict__ uu,
    const float* __restrict__ Wfc, const float* __restrict__ bfc,
    float* __restrict__ outp, unsigned short* smem)
{
  unsigned short (*XT)[KH + 8] = (unsigned short (*)[KH + 8])smem;
  float* fcbuf = (float*)(smem + 21504);
  int t = threadIdx.x, b = t & 63, w = t >> 6;
  int r = t & 15, g = (t >> 4) & 3;
  constexpr int OT = (MODE == 0) ? 2 : 1;
  constexpr int NST = (KPAD + KH - 1) / KH;

  for (int n = blockIdx.x; n < NN; n += NBLK){
    __syncthreads();                        // prev unit's LDS reads done
    if (FC && t < 64) fcbuf[t] = 0.f;

    float4v acc[OT][4];
    #pragma unroll
    for (int j = 0; j < OT; ++j)
      #pragma unroll
      for (int nt = 0; nt < 4; ++nt) acc[j][nt] = (float4v){0.f,0.f,0.f,0.f};

    #pragma unroll
    for (int st = 0; st < NST; ++st){
      const int kbase = st*KH;
      const int klen = (KPAD - kbase) < KH ? (KPAD - kbase) : KH;
      for (int o8 = w; o8 < klen/8; o8 += 4){
        int k0 = o8*8;
        short8v pk;
        #pragma unroll
        for (int i = 0; i < 8; ++i)
          pk[i] = (short)mats[((size_t)n*KPAD + kbase + k0 + i)*64 + b];
        *(short8v*)&XT[b][k0] = pk;
      }
      __syncthreads();
      for (int kc = 0; kc < klen/32; ++kc){
        short8v a[OT], bb[4];
        #pragma unroll
        for (int j = 0; j < OT; ++j){
          int o = (w + 4*j)*16 + r;
          a[j] = *(const short8v*)&Wt[(size_t)o*KPAD + kbase + kc*32 + g*8];
        }
        #pragma unroll
        for (int nt = 0; nt < 4; ++nt)
          bb[nt] = *(const short8v*)&XT[nt*16 + r][kc*32 + g*8];
        #pragma unroll
        for (int j = 0; j < OT; ++j)
          #pragma unroll
          for (int nt = 0; nt < 4; ++nt)
            acc[j][nt] = __builtin_amdgcn_mfma_f32_16x16x32_bf16(a[j], bb[nt], acc[j][nt], 0, 0, 0);
      }
      __syncthreads();
    }

    #pragma unroll
    for (int j = 0; j < OT; ++j){
      #pragma unroll
      for (int nt = 0; nt < 4; ++nt){
        int b2 = nt*16 + r;
        float p = 0.f;
        #pragma unroll
        for (int i = 0; i < 4; ++i){
          int o = (w + 4*j)*16 + g*4 + i;
          float v = acc[j][nt][i] + bias[o];
          if (MODE == 0){
            float sg = 1.f/(1.f + expf(-v));
            if (o < 64){
              size_t idx = (size_t)n*NODE + o*64 + b2;
              rh[idx] = sg * h[idx];
            } else {
              uu[(size_t)n*NODE + (o - 64)*64 + b2] = sg;
            }
          } else {
            float cv = tanhf(v);
            size_t idx = (size_t)n*NODE + o*64 + b2;
            float uv = uu[idx];
            float hn = uv*h[idx] + (1.f - uv)*cv;
            h[idx] = hn;
            if (FC) p += hn * Wfc[o];
          }
        }
        if (FC) atomicAdd(&fcbuf[b2], p);
      }
    }
    if (FC){
      __syncthreads();
      if (t < 64) outp[(size_t)t*NN + n] = fcbuf[t] + bfc[0];
    }
  }
}

static __device__ __forceinline__ void buildWt_dev(
    const float* __restrict__ W, unsigned short* __restrict__ Wt, int C, int O, int Kpad)
{
  int total = O*Kpad;
  for (int idx = blockIdx.x*256 + threadIdx.x; idx < total; idx += NBLK*256){
    int o = idx / Kpad, k = idx - o*Kpad;
    int m = k / C, c = k - m*C;
    Wt[idx] = f2bf(m < 5 ? W[(c*5 + m)*O + o] : 0.f);
  }
}

// ------------------------------------------------------ the whole model ----
__global__ __launch_bounds__(256, 1) void k_all(Args a){
  __shared__ __align__(16) unsigned short smem[23168];   // 46,336 B < 64 KB
  int lg = 0;
  const int tid = threadIdx.x;
  const int bx = blockIdx.x;
  const int lane = tid & 63, gq = tid >> 6;

  // ============ phase 0: sums + Wt + out0 + transposes ============
  {
    float* red = (float*)smem;
    for (int j = bx; j < NN; j += NBLK){
      float rv = 0.f, cv = 0.f;
      for (int k = tid; k < NN; k += 256){
        rv += a.adj[j*NN + k];
        cv += a.adj[k*NN + j];
      }
      #pragma unroll
      for (int o = 32; o > 0; o >>= 1){
        rv += __shfl_down(rv, o);
        cv += __shfl_down(cv, o);
      }
      __syncthreads();
      if (lane == 0){ red[gq] = rv; red[4 + gq] = cv; }
      __syncthreads();
      if (tid == 0){
        a.rs[j] = red[0]+red[1]+red[2]+red[3];
        a.cs[j] = red[4]+red[5]+red[6]+red[7];
      }
    }
    buildWt_dev(a.Wg0, a.Wg0t, 65, 128, 352);
    buildWt_dev(a.Wc0, a.Wc0t, 65,  64, 352);
    buildWt_dev(a.Wg1, a.Wg1t, 128, 128, 640);
    buildWt_dev(a.Wc1, a.Wc1t, 128,  64, 640);
    for (int i = bx*256 + tid; i < BB*NN; i += NBLK*256) a.out[i] = 0.f;

    float (*tile)[65] = (float (*)[65])smem;
    for (int u = bx; u < TT*6; u += NBLK){          // inpT
      int tt2 = u / 6, n0 = (u - tt2*6)*64;
      __syncthreads();
      #pragma unroll
      for (int r = 0; r < 16; ++r){
        int b = r*4 + gq;
        tile[b][lane] = (n0 + lane < NN) ? a.inp[(tt2*BB + b)*NN + n0 + lane] : 0.f;
      }
      __syncthreads();
      #pragma unroll
      for (int r = 0; r < 16; ++r){
        int c2 = r*4 + gq;
        if (n0 + c2 < NN) a.inpT[(size_t)tt2*(NN*64) + (n0 + c2)*64 + lane] = tile[lane][c2];
      }
    }
    for (int u = bx; u < 2*NN; u += NBLK){          // initT
      int n = u % NN, l = u / NN;
      const float* src = a.init + (size_t)l*BB*NN*64;
      float* dst = l ? a.h1 : a.h0;
      __syncthreads();
      #pragma unroll
      for (int r = 0; r < 16; ++r){
        int b = r*4 + gq;
        tile[b][lane] = src[(size_t)b*NN*64 + n*64 + lane];
      }
      __syncthreads();
      #pragma unroll
      for (int r = 0; r < 16; ++r){
        int c2 = r*4 + gq;
        dst[(size_t)n*NODE + c2*64 + lane] = tile[lane][c2];
      }
    }
  }
  gbar(a.bar, lg);

  // ============ phase 1: bf16 S build ============
  for (int idx = bx*256 + tid; idx < 2*NPADR*KD; idx += NBLK*256){
    int s = idx / (NPADR*KD);
    int rem = idx - s*(NPADR*KD);
    int i = rem / KD, j = rem - i*KD;
    float v = 0.f;
    if (i < NN && j < NN)
      v = (s == 0) ? a.adj[j*NN + i]/a.rs[j] : a.adj[i*NN + j]/a.cs[j];
    a.Sb[idx] = f2bf(v);
  }
  gbar(a.bar, lg);

  // ============ 12-step recurrence ============
  for (int t = 0; t < TT; ++t){
    const float* xin = a.inpT + (size_t)t*NN*64;
    // ---- layer 0 gate ----
    diff_phase(a.Sb, xin, 64, 1, a.h0, a.matsL0, 65, 352, 0, 65, smem);
    gbar(a.bar, lg);
    wg_phase<352, 0, false>(a.matsL0, a.Wg0t, a.bg0, a.h0, a.rh, a.uu,
                            nullptr, nullptr, nullptr, smem);
    gbar(a.bar, lg);
    // ---- layer 0 candidate (c=0 x-part reused) ----
    diff_phase(a.Sb, xin, 64, 1, a.rh, a.matsL0, 65, 352, 1, 64, smem);
    gbar(a.bar, lg);
    wg_phase<352, 1, false>(a.matsL0, a.Wc0t, a.bc0, a.h0, a.rh, a.uu,
                            nullptr, nullptr, nullptr, smem);
    gbar(a.bar, lg);
    // ---- layer 1 gate ----
    diff_phase(a.Sb, a.h0, NODE, 64, a.h1, a.matsL1, 128, 640, 0, 128, smem);
    gbar(a.bar, lg);
    wg_phase<640, 0, false>(a.matsL1, a.Wg1t, a.bg1, a.h1, a.rh, a.uu,
                            nullptr, nullptr, nullptr, smem);
    gbar(a.bar, lg);
    // ---- layer 1 candidate (c<64 x-part reused) + fused fc ----
    diff_phase(a.Sb, a.h0, NODE, 64, a.rh, a.matsL1, 128, 640, 64, 64, smem);
    gbar(a.bar, lg);
    wg_phase<640, 1, true>(a.matsL1, a.Wc1t, a.bc1, a.h1, a.rh, a.uu,
                           a.Wfc, a.bfc, a.out + (size_t)(t + 1)*BB*NN, smem);
    gbar(a.bar, lg);
  }
}

// ----------------------------------------------------------------- host ----
extern "C" void kernel_launch(void* const* d_in, const int* in_sizes, int n_in,
                              void* d_out, int out_size, void* d_ws, size_t ws_size,
                              hipStream_t stream){
  (void)in_sizes; (void)n_in; (void)out_size; (void)ws_size;
  char* p = (char*)d_ws;
  auto alloc = [&](size_t bytes) -> void* {
    void* q = (void*)p; p += (bytes + 255) & ~(size_t)255; return q;
  };
  Args a;
  a.inp  = (const float*)d_in[0];
  a.init = (const float*)d_in[1];
  a.adj  = (const float*)d_in[2];
  a.Wg0  = (const float*)d_in[3];
  a.bg0  = (const float*)d_in[4];
  a.Wc0  = (const float*)d_in[5];
  a.bc0  = (const float*)d_in[6];
  a.Wg1  = (const float*)d_in[7];
  a.bg1  = (const float*)d_in[8];
  a.Wc1  = (const float*)d_in[9];
  a.bc1  = (const float*)d_in[10];
  a.Wfc  = (const float*)d_in[11];
  a.bfc  = (const float*)d_in[12];
  a.bar   = (int*)alloc(256);
  a.Sb    = (unsigned short*)alloc((size_t)2*NPADR*KD*2);
  a.Wg0t  = (unsigned short*)alloc((size_t)128*352*2);
  a.Wc0t  = (unsigned short*)alloc((size_t)64*352*2);
  a.Wg1t  = (unsigned short*)alloc((size_t)128*640*2);
  a.Wc1t  = (unsigned short*)alloc((size_t)64*640*2);
  a.rs    = (float*)alloc(512*4);
  a.cs    = (float*)alloc(512*4);
  a.inpT  = (float*)alloc((size_t)TT*NN*64*4);
  a.h0    = (float*)alloc((size_t)NN*NODE*4);
  a.h1    = (float*)alloc((size_t)NN*NODE*4);
  a.rh    = (float*)alloc((size_t)NN*NODE*4);
  a.uu    = (float*)alloc((size_t)NN*NODE*4);
  a.matsL0 = (unsigned short*)alloc((size_t)NN*352*64*2);
  a.matsL1 = (unsigned short*)alloc((size_t)NN*640*64*2);
  a.out = (float*)d_out;

  hipMemsetAsync(a.bar, 0, 256, stream);       // barrier state must start at 0

  void* kargs[] = { &a };
  hipError_t e = hipLaunchCooperativeKernel((const void*)k_all, dim3(NBLK), dim3(256),
                                            kargs, 0, stream);
  if (e != hipSuccess){
    (void)hipGetLastError();                   // clear sticky error
    hipLaunchKernelGGL(k_all, dim3(NBLK), dim3(256), 0, stream, a);
  }
}

// Round 5
// 3575.313 us; speedup vs baseline: 3.1358x; 3.1358x over previous
//
#include <hip/hip_runtime.h>
#include <math.h>

#define NN    325
#define BB    64
#define TT    12
#define NODE  4096          // per-node stride of fp32 h/uu buffers: [n][c<64][b<64]
#define KD    352           // padded k-dim (nodes), 11*32
#define NPADR 384           // padded Scomb rows per matrix (24 tiles of 16)
#define XP    360           // LDS pitch for diff staging
#define KP0   352           // mats kk pitch, layer 0 (5*65=325 used)
#define KP1   640           // mats kk pitch, layer 1 (5*128)

typedef unsigned short ushort;
typedef __attribute__((ext_vector_type(8))) short short8v;
typedef __attribute__((ext_vector_type(4))) float float4v;

static __device__ __forceinline__ ushort f2bf(float f){
  unsigned u = __builtin_bit_cast(unsigned, f);
  u += 0x7fffu + ((u >> 16) & 1u);          // RNE
  return (ushort)(u >> 16);
}

// ---------------------------------------------------------------- setup ----
// row/col sums of adj; one block per row j
__global__ void k_sums(const float* __restrict__ adj, float* __restrict__ rs,
                       float* __restrict__ cs){
  __shared__ float red[8];
  int j = blockIdx.x;
  int tid = threadIdx.x, gq = tid >> 6;
  float rv = 0.f, cv = 0.f;
  for (int k = tid; k < NN; k += 256){
    rv += adj[j*NN + k];
    cv += adj[k*NN + j];
  }
  #pragma unroll
  for (int o = 32; o > 0; o >>= 1){
    rv += __shfl_down(rv, o);
    cv += __shfl_down(cv, o);
  }
  if ((tid & 63) == 0){ red[gq] = rv; red[4 + gq] = cv; }
  __syncthreads();
  if (tid == 0){
    rs[j] = red[0]+red[1]+red[2]+red[3];
    cs[j] = red[4]+red[5]+red[6]+red[7];
  }
}

// Sfp[0][i][j] = S1 = adj[j][i]/rs[j];  Sfp[1][i][j] = S2 = adj[i][j]/cs[j]
__global__ void k_Sfp(const float* __restrict__ adj, const float* __restrict__ rs,
                      const float* __restrict__ cs, float* __restrict__ Sfp){
  int idx = blockIdx.x*256 + threadIdx.x;
  if (idx >= NN*NN) return;
  int i = idx / NN, j = idx - i*NN;
  Sfp[idx]         = adj[j*NN + i] / rs[j];
  Sfp[NN*NN + idx] = adj[i*NN + j] / cs[j];
}

// Scomb (bf16, 4 stacked [NPADR][KD], pre-zeroed): [S1, 2S1^2-I, S2, 2S2^2-I]
__global__ void k_scomb(const float* __restrict__ Sfp, ushort* __restrict__ Scomb){
  int i = blockIdx.x, s = blockIdx.y;
  int tid = threadIdx.x;
  const float* S = Sfp + (size_t)s*NN*NN;
  float a0 = 0.f, a1 = 0.f;
  for (int k = 0; k < NN; ++k){
    float sik = S[i*NN + k];
    a0 += sik * S[k*NN + tid];
    if (tid + 256 < NN) a1 += sik * S[k*NN + tid + 256];
  }
  ushort* b0 = Scomb + (size_t)(2*s)*NPADR*KD + (size_t)i*KD;
  ushort* b1 = Scomb + (size_t)(2*s + 1)*NPADR*KD + (size_t)i*KD;
  b0[tid] = f2bf(S[i*NN + tid]);
  b1[tid] = f2bf(2.f*a0 - (i == tid ? 1.f : 0.f));
  if (tid + 256 < NN){
    b0[tid + 256] = f2bf(S[i*NN + tid + 256]);
    b1[tid + 256] = f2bf(2.f*a1 - (i == tid + 256 ? 1.f : 0.f));
  }
}

// Wt[o][kk], kk = m*C + c, from W[(c*5+m)*O + o]; zero for kk >= 5C
__global__ void k_wt(const float* __restrict__ W, ushort* __restrict__ Wt,
                     int C, int O, int Kpad){
  int idx = blockIdx.x*256 + threadIdx.x;
  int o = idx / Kpad, k = idx - o*Kpad;
  int m = k / C, c = k - m*C;
  Wt[idx] = f2bf(m < 5 ? W[(c*5 + m)*O + o] : 0.f);
}

// populate h0/h1 fp32 and mats slot-0 channels (x_0, h0, h1)
__global__ void k_init(const float* __restrict__ inp, const float* __restrict__ init,
                       float* __restrict__ h0, float* __restrict__ h1,
                       ushort* __restrict__ matsL0, ushort* __restrict__ matsL1){
  int n = blockIdx.x;
  int t = threadIdx.x, b = t & 63, cq = t >> 6;
  #pragma unroll
  for (int ii = 0; ii < 16; ++ii){
    int c = cq*16 + ii;
    float h0v = init[(size_t)(b*NN + n)*64 + c];
    float h1v = init[(size_t)BB*NN*64 + (size_t)(b*NN + n)*64 + c];
    h0[(size_t)n*NODE + c*64 + b] = h0v;
    h1[(size_t)n*NODE + c*64 + b] = h1v;
    matsL0[((size_t)n*KP0 + 1 + c)*64 + b]  = f2bf(h0v);
    matsL1[((size_t)n*KP1 + c)*64 + b]      = f2bf(h0v);
    matsL1[((size_t)n*KP1 + 64 + c)*64 + b] = f2bf(h1v);
  }
  if (t < 64)
    matsL0[((size_t)n*KP0)*64 + t] = f2bf(inp[(size_t)t*NN + n]);
}

// -------------------------------------------------- diffusion (4 passes) ----
// per block: channel c = c0+bx, row-half rh2. Stages slot-0 channel c once,
// then mats[kk=(1+m)*C+c] = Scomb_m @ x0  for m = 0..3 (Cheb folded into Scomb).
__global__ __launch_bounds__(256) void k_diff(
    const ushort* __restrict__ Scomb, ushort* __restrict__ mats,
    int KPAD, int C, int c0)
{
  __shared__ ushort X[64][XP];
  int c = c0 + blockIdx.x;
  int rh2 = blockIdx.y;
  int t = threadIdx.x, b = t & 63, w = t >> 6;
  int r = t & 15, g = (t >> 4) & 3;

  for (int o8 = w; o8 < KD/8; o8 += 4){
    int n0 = o8*8;
    short8v pk;
    #pragma unroll
    for (int i = 0; i < 8; ++i){
      int n = n0 + i;
      pk[i] = (n < NN) ? (short)mats[((size_t)n*KPAD + c)*64 + b] : (short)0;
    }
    *(short8v*)&X[b][n0] = pk;
  }
  __syncthreads();

  for (int m = 0; m < 4; ++m){
    const ushort* S = Scomb + ((size_t)m*NPADR + rh2*192)*KD;
    float4v acc[3][4];
    #pragma unroll
    for (int i = 0; i < 3; ++i)
      #pragma unroll
      for (int q = 0; q < 4; ++q) acc[i][q] = (float4v){0.f,0.f,0.f,0.f};
    for (int kc = 0; kc < KD/32; ++kc){
      short8v a[3], bb[4];
      #pragma unroll
      for (int mt = 0; mt < 3; ++mt)
        a[mt] = *(const short8v*)&S[(size_t)((w*3 + mt)*16 + r)*KD + kc*32 + g*8];
      #pragma unroll
      for (int nt = 0; nt < 4; ++nt)
        bb[nt] = *(const short8v*)&X[nt*16 + r][kc*32 + g*8];
      #pragma unroll
      for (int mt = 0; mt < 3; ++mt)
        #pragma unroll
        for (int nt = 0; nt < 4; ++nt)
          acc[mt][nt] = __builtin_amdgcn_mfma_f32_16x16x32_bf16(a[mt], bb[nt], acc[mt][nt], 0, 0, 0);
    }
    size_t kkb = (size_t)(1 + m)*C + c;
    #pragma unroll
    for (int mt = 0; mt < 3; ++mt){
      int node0 = rh2*192 + (w*3 + mt)*16 + g*4;
      #pragma unroll
      for (int nt = 0; nt < 4; ++nt){
        int col = nt*16 + r;
        #pragma unroll
        for (int i = 0; i < 4; ++i){
          int n = node0 + i;
          if (n < NN)
            mats[((size_t)n*KPAD + kkb)*64 + col] = f2bf(acc[mt][nt][i]);
        }
      }
    }
  }
}

// ------------------------------------------------------- W-GEMM (MFMA) ----
// MODE 0 (gate, O=128): o<64 -> rh = sigm*h  (bf16 -> dstA);  o>=64 -> uu = sigm
// MODE 1 (cand, O=64):  hn = u*h + (1-u)*tanh -> h fp32, bf16 -> dstA (+dstB);
//                       optional fused fc (outp) and next-x copy (xnext->xdst)
template<int KPAD, int MODE>
__global__ __launch_bounds__(256) void k_wg(
    const ushort* __restrict__ mats, const ushort* __restrict__ Wt,
    const float* __restrict__ bias, float* __restrict__ h, float* __restrict__ uu,
    ushort* __restrict__ dstA, int pA, ushort* __restrict__ dstB, int pB,
    const float* __restrict__ Wfc, const float* __restrict__ bfc,
    float* __restrict__ outp, const float* __restrict__ xnext,
    ushort* __restrict__ xdst, int pX)
{
  constexpr int KH  = (KPAD <= 352) ? KPAD : 320;
  constexpr int KHP = KH + 8;
  constexpr int NST = KPAD / KH;
  constexpr int OT  = (MODE == 0) ? 2 : 1;
  __shared__ ushort XT[64][KHP];
  __shared__ float fcbuf[64];
  int n = blockIdx.x;
  int t = threadIdx.x, b = t & 63, w = t >> 6;
  int r = t & 15, g = (t >> 4) & 3;
  const bool fc = (MODE == 1) && (outp != nullptr);
  if (fc && t < 64) fcbuf[t] = 0.f;

  float4v acc[OT][4];
  #pragma unroll
  for (int j = 0; j < OT; ++j)
    #pragma unroll
    for (int nt = 0; nt < 4; ++nt) acc[j][nt] = (float4v){0.f,0.f,0.f,0.f};

  #pragma unroll
  for (int st = 0; st < NST; ++st){
    const int kbase = st*KH;
    if (st) __syncthreads();
    for (int o8 = w; o8 < KH/8; o8 += 4){
      int k0 = o8*8;
      short8v pk;
      #pragma unroll
      for (int i = 0; i < 8; ++i)
        pk[i] = (short)mats[((size_t)n*KPAD + kbase + k0 + i)*64 + b];
      *(short8v*)&XT[b][k0] = pk;
    }
    __syncthreads();
    for (int kc = 0; kc < KH/32; ++kc){
      short8v a[OT], bb[4];
      #pragma unroll
      for (int j = 0; j < OT; ++j){
        int o = (w + 4*j)*16 + r;
        a[j] = *(const short8v*)&Wt[(size_t)o*KPAD + kbase + kc*32 + g*8];
      }
      #pragma unroll
      for (int nt = 0; nt < 4; ++nt)
        bb[nt] = *(const short8v*)&XT[nt*16 + r][kc*32 + g*8];
      #pragma unroll
      for (int j = 0; j < OT; ++j)
        #pragma unroll
        for (int nt = 0; nt < 4; ++nt)
          acc[j][nt] = __builtin_amdgcn_mfma_f32_16x16x32_bf16(a[j], bb[nt], acc[j][nt], 0, 0, 0);
    }
  }

  #pragma unroll
  for (int j = 0; j < OT; ++j){
    #pragma unroll
    for (int nt = 0; nt < 4; ++nt){
      int b2 = nt*16 + r;
      float p = 0.f;
      #pragma unroll
      for (int i = 0; i < 4; ++i){
        int o = (w + 4*j)*16 + g*4 + i;
        float v = acc[j][nt][i] + bias[o];
        if (MODE == 0){
          float sg = 1.f/(1.f + expf(-v));
          if (o < 64){
            size_t idx = (size_t)n*NODE + o*64 + b2;
            dstA[(size_t)n*pA*64 + (size_t)o*64 + b2] = f2bf(sg * h[idx]);
          } else {
            uu[(size_t)n*NODE + (o - 64)*64 + b2] = sg;
          }
        } else {
          float cv = tanhf(v);
          size_t idx = (size_t)n*NODE + o*64 + b2;
          float uv = uu[idx];
          float hn = uv*h[idx] + (1.f - uv)*cv;
          h[idx] = hn;
          ushort hb = f2bf(hn);
          dstA[(size_t)n*pA*64 + (size_t)o*64 + b2] = hb;
          if (dstB) dstB[(size_t)n*pB*64 + (size_t)o*64 + b2] = hb;
          if (fc) p += hn * Wfc[o];
        }
      }
      if (fc) atomicAdd(&fcbuf[b2], p);
    }
  }
  if (MODE == 1){
    if (xnext && t < 64)
      xdst[(size_t)n*pX*64 + t] = f2bf(xnext[(size_t)t*NN + n]);
    if (fc){
      __syncthreads();
      if (t < 64) outp[(size_t)t*NN + n] = fcbuf[t] + bfc[0];
    }
  }
}

// ----------------------------------------------------------------- host ----
extern "C" void kernel_launch(void* const* d_in, const int* in_sizes, int n_in,
                              void* d_out, int out_size, void* d_ws, size_t ws_size,
                              hipStream_t stream){
  const float* inp  = (const float*)d_in[0];
  const float* init = (const float*)d_in[1];
  const float* adj  = (const float*)d_in[2];
  const float* Wg0  = (const float*)d_in[3];
  const float* bg0  = (const float*)d_in[4];
  const float* Wc0  = (const float*)d_in[5];
  const float* bc0  = (const float*)d_in[6];
  const float* Wg1  = (const float*)d_in[7];
  const float* bg1  = (const float*)d_in[8];
  const float* Wc1  = (const float*)d_in[9];
  const float* bc1  = (const float*)d_in[10];
  const float* Wfc  = (const float*)d_in[11];
  const float* bfc  = (const float*)d_in[12];
  (void)in_sizes; (void)n_in; (void)out_size; (void)ws_size;

  char* p = (char*)d_ws;
  auto alloc = [&](size_t bytes) -> void* {
    void* q = (void*)p; p += (bytes + 255) & ~(size_t)255; return q;
  };
  ushort* Scomb = (ushort*)alloc((size_t)4*NPADR*KD*2);
  float*  Sfp   = (float*)alloc((size_t)2*NN*NN*4);
  ushort* Wg0t  = (ushort*)alloc((size_t)128*KP0*2);
  ushort* Wc0t  = (ushort*)alloc((size_t)64*KP0*2);
  ushort* Wg1t  = (ushort*)alloc((size_t)128*KP1*2);
  ushort* Wc1t  = (ushort*)alloc((size_t)64*KP1*2);
  float*  rs    = (float*)alloc(512*4);
  float*  cs    = (float*)alloc(512*4);
  float*  h0    = (float*)alloc((size_t)NN*NODE*4);
  float*  h1    = (float*)alloc((size_t)NN*NODE*4);
  float*  uu    = (float*)alloc((size_t)NN*NODE*4);
  ushort* matsL0 = (ushort*)alloc((size_t)NN*KP0*64*2);
  ushort* matsL1 = (ushort*)alloc((size_t)NN*KP1*64*2);
  float* out = (float*)d_out;

  hipMemsetAsync(out, 0, (size_t)BB*NN*4, stream);                 // out row 0
  hipMemsetAsync(matsL0, 0, (size_t)NN*KP0*64*2, stream);          // kk pad
  hipMemsetAsync(Scomb, 0, (size_t)4*NPADR*KD*2, stream);          // row/col pad

  k_sums<<<NN, 256, 0, stream>>>(adj, rs, cs);
  k_wt<<<(128*KP0)/256, 256, 0, stream>>>(Wg0, Wg0t, 65, 128, KP0);
  k_wt<<<( 64*KP0)/256, 256, 0, stream>>>(Wc0, Wc0t, 65,  64, KP0);
  k_wt<<<(128*KP1)/256, 256, 0, stream>>>(Wg1, Wg1t, 128, 128, KP1);
  k_wt<<<( 64*KP1)/256, 256, 0, stream>>>(Wc1, Wc1t, 128,  64, KP1);
  k_init<<<NN, 256, 0, stream>>>(inp, init, h0, h1, matsL0, matsL1);
  k_Sfp<<<(NN*NN + 255)/256, 256, 0, stream>>>(adj, rs, cs, Sfp);
  k_scomb<<<dim3(NN, 2), 256, 0, stream>>>(Sfp, Scomb);

  for (int t = 0; t < TT; ++t){
    // ---- layer 0 gate ----
    k_diff<<<dim3(65, 2), 256, 0, stream>>>(Scomb, matsL0, KP0, 65, 0);
    k_wg<KP0, 0><<<NN, 256, 0, stream>>>(matsL0, Wg0t, bg0, h0, uu,
        matsL0 + 1*64, KP0, nullptr, 0, nullptr, nullptr, nullptr, nullptr, nullptr, 0);
    // ---- layer 0 candidate (x-channel c=0 reused from gate) ----
    k_diff<<<dim3(64, 2), 256, 0, stream>>>(Scomb, matsL0, KP0, 65, 1);
    k_wg<KP0, 1><<<NN, 256, 0, stream>>>(matsL0, Wc0t, bc0, h0, uu,
        matsL0 + 1*64, KP0, matsL1, KP1, nullptr, nullptr, nullptr, nullptr, nullptr, 0);
    // ---- layer 1 gate ----
    k_diff<<<dim3(128, 2), 256, 0, stream>>>(Scomb, matsL1, KP1, 128, 0);
    k_wg<KP1, 0><<<NN, 256, 0, stream>>>(matsL1, Wg1t, bg1, h1, uu,
        matsL1 + 64*64, KP1, nullptr, 0, nullptr, nullptr, nullptr, nullptr, nullptr, 0);
    // ---- layer 1 candidate (x-channels c<64 reused) + fused fc + next-x ----
    k_diff<<<dim3(64, 2), 256, 0, stream>>>(Scomb, matsL1, KP1, 128, 64);
    const float* xn = (t + 1 < TT) ? inp + (size_t)(t + 1)*BB*NN : nullptr;
    k_wg<KP1, 1><<<NN, 256, 0, stream>>>(matsL1, Wc1t, bc1, h1, uu,
        matsL1 + 64*64, KP1, nullptr, 0, Wfc, bfc,
        out + (size_t)(t + 1)*BB*NN, xn, matsL0, KP0);
  }
}

// Round 7
// 3319.875 us; speedup vs baseline: 3.3771x; 1.0769x over previous
//
#include <hip/hip_runtime.h>
#include <math.h>

#define NN    325
#define BB    64
#define TT    12
#define NODE  4096          // per-node stride of fp32 h/uu buffers: [n][c<64][b<64]
#define KD    352           // padded k-dim (nodes), 11*32
#define NPADR 384           // padded Scomb rows per matrix (24 tiles of 16)
#define XP    360           // LDS pitch
#define KP0   352           // mats kk pitch, layer 0 (5*65=325 used)
#define KP1   640           // mats kk pitch, layer 1 (5*128)
#define SB2   512           // setup2 grid

typedef unsigned short ushort;
typedef __attribute__((ext_vector_type(8))) short short8v;
typedef __attribute__((ext_vector_type(4))) float float4v;

static __device__ __forceinline__ ushort f2bf(float f){
  unsigned u = __builtin_bit_cast(unsigned, f);
  u += 0x7fffu + ((u >> 16) & 1u);          // RNE
  return (ushort)(u >> 16);
}

// ---------------------------------------------------------------- setup ----
__global__ void k_sums(const float* __restrict__ adj, float* __restrict__ rs,
                       float* __restrict__ cs){
  __shared__ float red[8];
  int j = blockIdx.x;
  int tid = threadIdx.x, gq = tid >> 6;
  float rv = 0.f, cv = 0.f;
  for (int k = tid; k < NN; k += 256){
    rv += adj[j*NN + k];
    cv += adj[k*NN + j];
  }
  #pragma unroll
  for (int o = 32; o > 0; o >>= 1){
    rv += __shfl_down(rv, o);
    cv += __shfl_down(cv, o);
  }
  if ((tid & 63) == 0){ red[gq] = rv; red[4 + gq] = cv; }
  __syncthreads();
  if (tid == 0){
    rs[j] = red[0]+red[1]+red[2]+red[3];
    cs[j] = red[4]+red[5]+red[6]+red[7];
  }
}

// merged: Sfp + Scomb slots 0,2 + Wt transposes + h/mats init
__global__ void k_setup2(const float* __restrict__ adj, const float* __restrict__ rs,
                         const float* __restrict__ cs, const float* __restrict__ inp,
                         const float* __restrict__ init,
                         const float* __restrict__ Wg0, const float* __restrict__ Wc0,
                         const float* __restrict__ Wg1, const float* __restrict__ Wc1,
                         float* __restrict__ Sfp, ushort* __restrict__ Scomb,
                         ushort* __restrict__ Wg0t, ushort* __restrict__ Wc0t,
                         ushort* __restrict__ Wg1t, ushort* __restrict__ Wc1t,
                         float* __restrict__ h0, float* __restrict__ h1,
                         ushort* __restrict__ matsL0, ushort* __restrict__ matsL1){
  int bx = blockIdx.x, t = threadIdx.x;
  if (bx < NN){                       // init task: node bx
    int n = bx, b = t & 63, cq = t >> 6;
    #pragma unroll
    for (int ii = 0; ii < 16; ++ii){
      int c = cq*16 + ii;
      float h0v = init[(size_t)(b*NN + n)*64 + c];
      float h1v = init[(size_t)BB*NN*64 + (size_t)(b*NN + n)*64 + c];
      h0[(size_t)n*NODE + c*64 + b] = h0v;
      h1[(size_t)n*NODE + c*64 + b] = h1v;
      matsL0[((size_t)n*KP0 + 1 + c)*64 + b]  = f2bf(h0v);
      matsL1[((size_t)n*KP1 + c)*64 + b]      = f2bf(h0v);
      matsL1[((size_t)n*KP1 + 64 + c)*64 + b] = f2bf(h1v);
    }
    if (t < 64)
      matsL0[(size_t)n*KP0*64 + t] = f2bf(inp[(size_t)t*NN + n]);
  }
  for (int idx = bx*256 + t; idx < 2*NN*NN; idx += SB2*256){
    int s = idx / (NN*NN), rem = idx - s*(NN*NN);
    int i = rem / NN, j = rem - i*NN;
    float v = s ? adj[i*NN + j]/cs[j] : adj[j*NN + i]/rs[j];
    Sfp[idx] = v;
    Scomb[(size_t)(2*s)*NPADR*KD + (size_t)i*KD + j] = f2bf(v);
  }
  // Wt[o][k], k = m*C + c, from W[(c*5+m)*O + o]; zero for k >= 5C
  {
    const float* Ws[4] = { Wg0, Wc0, Wg1, Wc1 };
    ushort* Wts[4]     = { Wg0t, Wc0t, Wg1t, Wc1t };
    const int Cs[4] = { 65, 65, 128, 128 };
    const int Os[4] = { 128, 64, 128, 64 };
    const int Kp[4] = { KP0, KP0, KP1, KP1 };
    for (int q = 0; q < 4; ++q){
      int total = Os[q]*Kp[q];
      for (int idx = bx*256 + t; idx < total; idx += SB2*256){
        int o = idx / Kp[q], k = idx - o*Kp[q];
        int m = k / Cs[q], c = k - m*Cs[q];
        Wts[q][idx] = f2bf(m < 5 ? Ws[q][(c*5 + m)*Os[q] + o] : 0.f);
      }
    }
  }
}

// Scomb slots 1,3 = 2*S_s^2 - I via MFMA (A = Scomb slot 2s bf16, X staged from Sfp)
__global__ __launch_bounds__(256) void k_s2(const float* __restrict__ Sfp,
                                            ushort* __restrict__ Scomb){
  __shared__ ushort X[64][XP];
  int jt = blockIdx.x, rh2 = blockIdx.y, s = blockIdx.z;
  int t = threadIdx.x, w = t >> 6, r = t & 15, g = (t >> 4) & 3;
  const float* S = Sfp + (size_t)s*NN*NN;
  // stage X[j][k] = S[k][jt*64+j] for k in [0,KD), j in [0,64): KD*8 groups of 8
  for (int idx = t; idx < KD*8; idx += 256){
    int k = idx >> 3, j0 = (idx & 7)*8;
    #pragma unroll
    for (int i = 0; i < 8; ++i){
      int j = j0 + i, col = jt*64 + j;
      float v = (k < NN && col < NN) ? S[(size_t)k*NN + col] : 0.f;
      X[j][k] = f2bf(v);
    }
  }
  __syncthreads();
  const ushort* A = Scomb + (size_t)(2*s)*NPADR*KD + (size_t)(rh2*192)*KD;
  float4v acc[3][4];
  #pragma unroll
  for (int i = 0; i < 3; ++i)
    #pragma unroll
    for (int q = 0; q < 4; ++q) acc[i][q] = (float4v){0.f,0.f,0.f,0.f};
  for (int kc = 0; kc < KD/32; ++kc){
    short8v a[3], bbv[4];
    #pragma unroll
    for (int mt = 0; mt < 3; ++mt)
      a[mt] = *(const short8v*)&A[(size_t)((w*3 + mt)*16 + r)*KD + kc*32 + g*8];
    #pragma unroll
    for (int nt = 0; nt < 4; ++nt)
      bbv[nt] = *(const short8v*)&X[nt*16 + r][kc*32 + g*8];
    #pragma unroll
    for (int mt = 0; mt < 3; ++mt)
      #pragma unroll
      for (int nt = 0; nt < 4; ++nt)
        acc[mt][nt] = __builtin_amdgcn_mfma_f32_16x16x32_bf16(a[mt], bbv[nt], acc[mt][nt], 0, 0, 0);
  }
  ushort* dst = Scomb + (size_t)(2*s + 1)*NPADR*KD;
  #pragma unroll
  for (int mt = 0; mt < 3; ++mt){
    int node0 = rh2*192 + (w*3 + mt)*16 + g*4;
    #pragma unroll
    for (int nt = 0; nt < 4; ++nt){
      int col = nt*16 + r, jg = jt*64 + col;
      #pragma unroll
      for (int i = 0; i < 4; ++i){
        int n = node0 + i;
        if (n < NN && jg < NN)
          dst[(size_t)n*KD + jg] = f2bf(2.f*acc[mt][nt][i] - (n == jg ? 1.f : 0.f));
      }
    }
  }
}

// ----------------------------------------------- multi-segment diffusion ----
struct Seg {
  const ushort* sm;      // mats source (or null -> sf)
  const float*  sf;      // fp32 [b*NN + n] source (x channel); also writes slot 0
  ushort* dm;
  int KPs, KPd, C, cs0, cd0;
};
struct DiffA {
  const ushort* Sc;
  Seg seg[3];
  int e0, e1;            // seg0: [0,e0), seg1: [e0,e1), seg2: [e1, ...)
};

template<int MT>
__global__ __launch_bounds__(256) void k_diffN(DiffA da){
  __shared__ ushort X[64][XP];
  int bx = blockIdx.x;
  Seg sg; int u;
  if (bx < da.e0){ sg = da.seg[0]; u = bx; }
  else if (bx < da.e1){ sg = da.seg[1]; u = bx - da.e0; }
  else { sg = da.seg[2]; u = bx - da.e1; }
  int t = threadIdx.x, b = t & 63, w = t >> 6;
  int r = t & 15, g = (t >> 4) & 3;

  if (sg.sm){
    const ushort* src = sg.sm + (size_t)(sg.cs0 + u)*64 + b;
    for (int o8 = w; o8 < KD/8; o8 += 4){
      int n0 = o8*8;
      short8v pk;
      #pragma unroll
      for (int i = 0; i < 8; ++i){
        int n = n0 + i;
        pk[i] = (n < NN) ? (short)src[(size_t)n*(sg.KPs*64)] : (short)0;
      }
      *(short8v*)&X[b][n0] = pk;
    }
  } else {
    for (int idx = t; idx < 64*(KD/8); idx += 256){
      int bb2 = idx / (KD/8);
      int n0 = (idx - bb2*(KD/8))*8;
      #pragma unroll
      for (int i = 0; i < 8; ++i){
        int n = n0 + i;
        ushort us = 0;
        if (n < NN){
          us = f2bf(sg.sf[(size_t)bb2*NN + n]);
          sg.dm[(size_t)n*(sg.KPd*64) + bb2] = us;      // slot 0 (x channel)
        }
        X[bb2][n] = us;
      }
    }
  }
  __syncthreads();

  for (int m = 0; m < 4; ++m){
    const ushort* S = da.Sc + ((size_t)m*NPADR + (size_t)blockIdx.y*(MT*64))*KD;
    float4v acc[MT][4];
    #pragma unroll
    for (int i = 0; i < MT; ++i)
      #pragma unroll
      for (int q = 0; q < 4; ++q) acc[i][q] = (float4v){0.f,0.f,0.f,0.f};
    for (int kc = 0; kc < KD/32; ++kc){
      short8v a[MT], bbv[4];
      #pragma unroll
      for (int mt = 0; mt < MT; ++mt)
        a[mt] = *(const short8v*)&S[(size_t)((w*MT + mt)*16 + r)*KD + kc*32 + g*8];
      #pragma unroll
      for (int nt = 0; nt < 4; ++nt)
        bbv[nt] = *(const short8v*)&X[nt*16 + r][kc*32 + g*8];
      #pragma unroll
      for (int mt = 0; mt < MT; ++mt)
        #pragma unroll
        for (int nt = 0; nt < 4; ++nt)
          acc[mt][nt] = __builtin_amdgcn_mfma_f32_16x16x32_bf16(a[mt], bbv[nt], acc[mt][nt], 0, 0, 0);
    }
    ushort* dst = sg.dm + ((size_t)(1 + m)*sg.C + sg.cd0 + u)*64;
    #pragma unroll
    for (int mt = 0; mt < MT; ++mt){
      int node0 = blockIdx.y*(MT*64) + (w*MT + mt)*16 + g*4;
      #pragma unroll
      for (int nt = 0; nt < 4; ++nt){
        int col = nt*16 + r;
        #pragma unroll
        for (int i = 0; i < 4; ++i){
          int n = node0 + i;
          if (n < NN) dst[(size_t)n*(sg.KPd*64) + col] = f2bf(acc[mt][nt][i]);
        }
      }
    }
  }
}

// ------------------------------------------- dual-descriptor W-GEMM (MFMA) ----
struct WgD {
  const ushort* mats; const ushort* Wt; const float* bias;
  float* h; float* uu;
  ushort* dstA; int pA; ushort* dstB; int pB;
  const float* Wfc; const float* bfc; float* outp;
  int KPAD; int MODE;      // MODE 0: gate (O=128, rh+uu); 1: cand (O=64, h-update)
};

__global__ __launch_bounds__(256) void k_wg2(WgD d0, int n0, WgD d1){
  __shared__ ushort XT[64][XP];
  __shared__ float fcbuf[64];
  const bool first = (blockIdx.x < (unsigned)n0);
  WgD d = first ? d0 : d1;
  int n = first ? blockIdx.x : blockIdx.x - n0;
  int t = threadIdx.x, b = t & 63, w = t >> 6;
  int r = t & 15, g = (t >> 4) & 3;
  const int KPAD = d.KPAD;
  const int NST = (KPAD > 352) ? 2 : 1;
  const int KH  = (KPAD > 352) ? 320 : KPAD;
  const int OT  = (d.MODE == 0) ? 2 : 1;
  const bool fc = (d.MODE == 1) && (d.outp != nullptr);
  if (fc && t < 64) fcbuf[t] = 0.f;

  float4v acc[2][4];
  #pragma unroll
  for (int j = 0; j < 2; ++j)
    #pragma unroll
    for (int nt = 0; nt < 4; ++nt) acc[j][nt] = (float4v){0.f,0.f,0.f,0.f};

  for (int st = 0; st < NST; ++st){
    int kbase = st*KH;
    if (st) __syncthreads();
    for (int o8 = w; o8 < KH/8; o8 += 4){
      int k0 = o8*8;
      short8v pk;
      #pragma unroll
      for (int i = 0; i < 8; ++i)
        pk[i] = (short)d.mats[((size_t)n*KPAD + kbase + k0 + i)*64 + b];
      *(short8v*)&XT[b][k0] = pk;
    }
    __syncthreads();
    for (int kc = 0; kc < KH/32; ++kc){
      short8v a0, a1, bbv[4];
      a0 = *(const short8v*)&d.Wt[(size_t)(w*16 + r)*KPAD + kbase + kc*32 + g*8];
      if (OT == 2)
        a1 = *(const short8v*)&d.Wt[(size_t)((w + 4)*16 + r)*KPAD + kbase + kc*32 + g*8];
      #pragma unroll
      for (int nt = 0; nt < 4; ++nt)
        bbv[nt] = *(const short8v*)&XT[nt*16 + r][kc*32 + g*8];
      #pragma unroll
      for (int nt = 0; nt < 4; ++nt)
        acc[0][nt] = __builtin_amdgcn_mfma_f32_16x16x32_bf16(a0, bbv[nt], acc[0][nt], 0, 0, 0);
      if (OT == 2)
        #pragma unroll
        for (int nt = 0; nt < 4; ++nt)
          acc[1][nt] = __builtin_amdgcn_mfma_f32_16x16x32_bf16(a1, bbv[nt], acc[1][nt], 0, 0, 0);
    }
  }

  for (int j = 0; j < OT; ++j){
    #pragma unroll
    for (int nt = 0; nt < 4; ++nt){
      int b2 = nt*16 + r;
      float p = 0.f;
      #pragma unroll
      for (int i = 0; i < 4; ++i){
        int o = (w + 4*j)*16 + g*4 + i;
        float v = acc[j][nt][i] + d.bias[o];
        if (d.MODE == 0){
          float sg = 1.f/(1.f + expf(-v));
          if (o < 64){
            size_t idx = (size_t)n*NODE + o*64 + b2;
            d.dstA[(size_t)n*(d.pA*64) + (size_t)o*64 + b2] = f2bf(sg * d.h[idx]);
          } else {
            d.uu[(size_t)n*NODE + (o - 64)*64 + b2] = sg;
          }
        } else {
          float cv = tanhf(v);
          size_t idx = (size_t)n*NODE + o*64 + b2;
          float uv = d.uu[idx];
          float hn = uv*d.h[idx] + (1.f - uv)*cv;
          d.h[idx] = hn;
          ushort hb = f2bf(hn);
          d.dstA[(size_t)n*(d.pA*64) + (size_t)o*64 + b2] = hb;
          if (d.dstB) d.dstB[(size_t)n*(d.pB*64) + (size_t)o*64 + b2] = hb;
          if (fc) p += hn * d.Wfc[o];
        }
      }
      if (fc) atomicAdd(&fcbuf[b2], p);
    }
  }
  if (fc){
    __syncthreads();
    if (t < 64) d.outp[(size_t)t*NN + n] = fcbuf[t] + d.bfc[0];
  }
}

// ----------------------------------------------------------------- host ----
extern "C" void kernel_launch(void* const* d_in, const int* in_sizes, int n_in,
                              void* d_out, int out_size, void* d_ws, size_t ws_size,
                              hipStream_t stream){
  const float* inp  = (const float*)d_in[0];
  const float* init = (const float*)d_in[1];
  const float* adj  = (const float*)d_in[2];
  const float* Wg0  = (const float*)d_in[3];
  const float* bg0  = (const float*)d_in[4];
  const float* Wc0  = (const float*)d_in[5];
  const float* bc0  = (const float*)d_in[6];
  const float* Wg1  = (const float*)d_in[7];
  const float* bg1  = (const float*)d_in[8];
  const float* Wc1  = (const float*)d_in[9];
  const float* bc1  = (const float*)d_in[10];
  const float* Wfc  = (const float*)d_in[11];
  const float* bfc  = (const float*)d_in[12];
  (void)in_sizes; (void)n_in; (void)out_size; (void)ws_size;

  char* p = (char*)d_ws;
  auto alloc = [&](size_t bytes) -> void* {
    void* q = (void*)p; p += (bytes + 255) & ~(size_t)255; return q;
  };
  ushort* Scomb  = (ushort*)alloc((size_t)4*NPADR*KD*2);
  float*  Sfp    = (float*)alloc((size_t)2*NN*NN*4);
  ushort* Wg0t   = (ushort*)alloc((size_t)128*KP0*2);
  ushort* Wc0t   = (ushort*)alloc((size_t)64*KP0*2);
  ushort* Wg1t   = (ushort*)alloc((size_t)128*KP1*2);
  ushort* Wc1t   = (ushort*)alloc((size_t)64*KP1*2);
  float*  rs     = (float*)alloc(512*4);
  float*  cs     = (float*)alloc(512*4);
  float*  h0     = (float*)alloc((size_t)NN*NODE*4);
  float*  h1     = (float*)alloc((size_t)NN*NODE*4);
  float*  uu0    = (float*)alloc((size_t)NN*NODE*4);
  float*  uu1    = (float*)alloc((size_t)NN*NODE*4);
  ushort* matsL0 = (ushort*)alloc((size_t)NN*KP0*64*2);
  ushort* matsL1 = (ushort*)alloc((size_t)NN*KP1*64*2);
  float* out = (float*)d_out;

  hipMemsetAsync(out, 0, (size_t)BB*NN*4, stream);
  hipMemsetAsync(matsL0, 0, (size_t)NN*KP0*64*2, stream);
  hipMemsetAsync(Scomb, 0, (size_t)4*NPADR*KD*2, stream);

  k_sums<<<NN, 256, 0, stream>>>(adj, rs, cs);
  k_setup2<<<SB2, 256, 0, stream>>>(adj, rs, cs, inp, init, Wg0, Wc0, Wg1, Wc1,
                                    Sfp, Scomb, Wg0t, Wc0t, Wg1t, Wc1t,
                                    h0, h1, matsL0, matsL1);
  k_s2<<<dim3(6, 2, 2), 256, 0, stream>>>(Sfp, Scomb);

  Seg segL0g  = { matsL0, nullptr, matsL0, KP0, KP0, 65, 0, 0 };     // full gate L0 (65 ch)
  Seg segL0c  = { matsL0, nullptr, matsL0, KP0, KP0, 65, 1, 1 };     // rh / h0 (64 ch)
  Seg segL1h1 = { matsL1, nullptr, matsL1, KP1, KP1, 128, 64, 64 };  // h1 / rh1 (64 ch)
  Seg segL1h0 = { matsL1, nullptr, matsL1, KP1, KP1, 128, 0, 0 };    // h0-part (64 ch)

  // priming: full L0-gate diffusion (x_0 + h0)
  { DiffA da = { Scomb, { segL0g, segL0g, segL0g }, 65, 65 };
    k_diffN<3><<<dim3(65, 2), 256, 0, stream>>>(da); }

  WgD wg_g0 = { matsL0, Wg0t, bg0, h0, uu0, matsL0 + 64, KP0, nullptr, 0,
                nullptr, nullptr, nullptr, KP0, 0 };
  WgD wg_c0 = { matsL0, Wc0t, bc0, h0, uu0, matsL0 + 64, KP0, matsL1, KP1,
                nullptr, nullptr, nullptr, KP0, 1 };
  WgD wg_g1 = { matsL1, Wg1t, bg1, h1, uu1, matsL1 + 64*64, KP1, nullptr, 0,
                nullptr, nullptr, nullptr, KP1, 0 };

  k_wg2<<<NN, 256, 0, stream>>>(wg_g0, NN, wg_g0);        // wg L0-gate, t=0

  for (int t = 0; t < TT; ++t){
    // P2: L0-cand diff (rh) + L1-gate diff h1-part
    { DiffA da = { Scomb, { segL0c, segL1h1, segL0c }, 64, 128 };
      k_diffN<3><<<dim3(128, 2), 256, 0, stream>>>(da); }
    // P3: wg L0-cand -> h0_new
    k_wg2<<<NN, 256, 0, stream>>>(wg_c0, NN, wg_c0);
    // P4: L1-gate diff h0-part + next-L0-gate diff h0-part + x_{t+1} channel
    { Seg segX = { nullptr, inp + (size_t)(t + 1)*BB*NN, matsL0, 0, KP0, 65, 0, 0 };
      DiffA da = { Scomb, { segL1h0, segL0c, segX }, 64, 128 };
      k_diffN<3><<<dim3(129, 2), 256, 0, stream>>>(da); }
    // P5: wg L1-gate -> rh1 + uu1
    k_wg2<<<NN, 256, 0, stream>>>(wg_g1, NN, wg_g1);
    // P6: L1-cand diff (rh1)
    { DiffA da = { Scomb, { segL1h1, segL1h1, segL1h1 }, 64, 64 };
      k_diffN<2><<<dim3(64, 3), 256, 0, stream>>>(da); }
    // P7: wg L1-cand (+fc)  [merged with next step's wg L0-gate]
    WgD wg_c1 = { matsL1, Wc1t, bc1, h1, uu1, matsL1 + 64*64, KP1, nullptr, 0,
                  Wfc, bfc, out + (size_t)(t + 1)*BB*NN, KP1, 1 };
    if (t < TT - 1)
      k_wg2<<<2*NN, 256, 0, stream>>>(wg_c1, NN, wg_g0);
    else
      k_wg2<<<NN, 256, 0, stream>>>(wg_c1, NN, wg_c1);
  }
}

// Round 8
// 3279.869 us; speedup vs baseline: 3.4183x; 1.0122x over previous
//
#include <hip/hip_runtime.h>
#include <math.h>

#define NN    325
#define BB    64
#define TT    12
#define NODE  4096          // per-node stride of fp32 h/uu buffers: [n][c<64][b<64]
#define KD    352           // padded k-dim (nodes), 11*32
#define NPADR 384           // padded Scomb rows per matrix (24 tiles of 16)
#define XP    360           // LDS pitch
#define KP0   352           // mats kk count, layer 0 (5*65=325 used)
#define KP1   640           // mats kk count, layer 1 (5*128)
#define SB2   512           // setup2 grid
// mats layout (kk-major): mats[(kk*NN + n)*64 + b]

typedef unsigned short ushort;
typedef __attribute__((ext_vector_type(8))) short short8v;
typedef __attribute__((ext_vector_type(4))) float float4v;

static __device__ __forceinline__ ushort f2bf(float f){
  unsigned u = __builtin_bit_cast(unsigned, f);
  u += 0x7fffu + ((u >> 16) & 1u);          // RNE
  return (ushort)(u >> 16);
}

// ---------------------------------------------------------------- setup ----
__global__ void k_sums(const float* __restrict__ adj, float* __restrict__ rs,
                       float* __restrict__ cs){
  __shared__ float red[8];
  int j = blockIdx.x;
  int tid = threadIdx.x, gq = tid >> 6;
  float rv = 0.f, cv = 0.f;
  for (int k = tid; k < NN; k += 256){
    rv += adj[j*NN + k];
    cv += adj[k*NN + j];
  }
  #pragma unroll
  for (int o = 32; o > 0; o >>= 1){
    rv += __shfl_down(rv, o);
    cv += __shfl_down(cv, o);
  }
  if ((tid & 63) == 0){ red[gq] = rv; red[4 + gq] = cv; }
  __syncthreads();
  if (tid == 0){
    rs[j] = red[0]+red[1]+red[2]+red[3];
    cs[j] = red[4]+red[5]+red[6]+red[7];
  }
}

// merged: Sfp + Scomb slots 0,2 + Wt transposes + h/mats init
__global__ void k_setup2(const float* __restrict__ adj, const float* __restrict__ rs,
                         const float* __restrict__ cs, const float* __restrict__ inp,
                         const float* __restrict__ init,
                         const float* __restrict__ Wg0, const float* __restrict__ Wc0,
                         const float* __restrict__ Wg1, const float* __restrict__ Wc1,
                         float* __restrict__ Sfp, ushort* __restrict__ Scomb,
                         ushort* __restrict__ Wg0t, ushort* __restrict__ Wc0t,
                         ushort* __restrict__ Wg1t, ushort* __restrict__ Wc1t,
                         float* __restrict__ h0, float* __restrict__ h1,
                         ushort* __restrict__ matsL0, ushort* __restrict__ matsL1){
  int bx = blockIdx.x, t = threadIdx.x;
  if (bx < NN){                       // init task: node bx
    int n = bx, b = t & 63, cq = t >> 6;
    #pragma unroll
    for (int ii = 0; ii < 16; ++ii){
      int c = cq*16 + ii;
      float h0v = init[(size_t)(b*NN + n)*64 + c];
      float h1v = init[(size_t)BB*NN*64 + (size_t)(b*NN + n)*64 + c];
      h0[(size_t)n*NODE + c*64 + b] = h0v;
      h1[(size_t)n*NODE + c*64 + b] = h1v;
      matsL0[((size_t)(1 + c)*NN + n)*64 + b]  = f2bf(h0v);
      matsL1[((size_t)c*NN + n)*64 + b]        = f2bf(h0v);
      matsL1[((size_t)(64 + c)*NN + n)*64 + b] = f2bf(h1v);
    }
    if (t < 64)
      matsL0[(size_t)n*64 + t] = f2bf(inp[(size_t)t*NN + n]);
  }
  for (int idx = bx*256 + t; idx < 2*NN*NN; idx += SB2*256){
    int s = idx / (NN*NN), rem = idx - s*(NN*NN);
    int i = rem / NN, j = rem - i*NN;
    float v = s ? adj[i*NN + j]/cs[j] : adj[j*NN + i]/rs[j];
    Sfp[idx] = v;
    Scomb[(size_t)(2*s)*NPADR*KD + (size_t)i*KD + j] = f2bf(v);
  }
  // Wt[o][k], k = m*C + c, from W[(c*5+m)*O + o]; zero for k >= 5C
  {
    const float* Ws[4] = { Wg0, Wc0, Wg1, Wc1 };
    ushort* Wts[4]     = { Wg0t, Wc0t, Wg1t, Wc1t };
    const int Cs[4] = { 65, 65, 128, 128 };
    const int Os[4] = { 128, 64, 128, 64 };
    const int Kp[4] = { KP0, KP0, KP1, KP1 };
    for (int q = 0; q < 4; ++q){
      int total = Os[q]*Kp[q];
      for (int idx = bx*256 + t; idx < total; idx += SB2*256){
        int o = idx / Kp[q], k = idx - o*Kp[q];
        int m = k / Cs[q], c = k - m*Cs[q];
        Wts[q][idx] = f2bf(m < 5 ? Ws[q][(c*5 + m)*Os[q] + o] : 0.f);
      }
    }
  }
}

// Scomb slots 1,3 = 2*S_s^2 - I via MFMA (A = Scomb slot 2s bf16, X staged from Sfp)
__global__ __launch_bounds__(256) void k_s2(const float* __restrict__ Sfp,
                                            ushort* __restrict__ Scomb){
  __shared__ ushort X[64][XP];
  int jt = blockIdx.x, rh2 = blockIdx.y, s = blockIdx.z;
  int t = threadIdx.x, w = t >> 6, r = t & 15, g = (t >> 4) & 3;
  const float* S = Sfp + (size_t)s*NN*NN;
  // stage X[j][k] = S[k][jt*64+j] for k in [0,KD), j in [0,64)
  for (int idx = t; idx < KD*8; idx += 256){
    int k = idx >> 3, j0 = (idx & 7)*8;
    #pragma unroll
    for (int i = 0; i < 8; ++i){
      int j = j0 + i, col = jt*64 + j;
      float v = (k < NN && col < NN) ? S[(size_t)k*NN + col] : 0.f;
      X[j][k] = f2bf(v);
    }
  }
  __syncthreads();
  const ushort* A = Scomb + (size_t)(2*s)*NPADR*KD + (size_t)(rh2*192)*KD;
  float4v acc[3][4];
  #pragma unroll
  for (int i = 0; i < 3; ++i)
    #pragma unroll
    for (int q = 0; q < 4; ++q) acc[i][q] = (float4v){0.f,0.f,0.f,0.f};
  for (int kc = 0; kc < KD/32; ++kc){
    short8v a[3], bbv[4];
    #pragma unroll
    for (int mt = 0; mt < 3; ++mt)
      a[mt] = *(const short8v*)&A[(size_t)((w*3 + mt)*16 + r)*KD + kc*32 + g*8];
    #pragma unroll
    for (int nt = 0; nt < 4; ++nt)
      bbv[nt] = *(const short8v*)&X[nt*16 + r][kc*32 + g*8];
    #pragma unroll
    for (int mt = 0; mt < 3; ++mt)
      #pragma unroll
      for (int nt = 0; nt < 4; ++nt)
        acc[mt][nt] = __builtin_amdgcn_mfma_f32_16x16x32_bf16(a[mt], bbv[nt], acc[mt][nt], 0, 0, 0);
  }
  ushort* dst = Scomb + (size_t)(2*s + 1)*NPADR*KD;
  #pragma unroll
  for (int mt = 0; mt < 3; ++mt){
    int node0 = rh2*192 + (w*3 + mt)*16 + g*4;
    #pragma unroll
    for (int nt = 0; nt < 4; ++nt){
      int col = nt*16 + r, jg = jt*64 + col;
      #pragma unroll
      for (int i = 0; i < 4; ++i){
        int n = node0 + i;
        if (n < NN && jg < NN)
          dst[(size_t)n*KD + jg] = f2bf(2.f*acc[mt][nt][i] - (n == jg ? 1.f : 0.f));
      }
    }
  }
}

// ----------------------------------------------- multi-segment diffusion ----
struct Seg {
  const ushort* sm;      // mats source channel base (or null -> sf)
  const float*  sf;      // fp32 [b*NN + n] source (x channel); also writes slot 0
  ushort* dm;
  int C, cs0, cd0;
};
struct DiffA {
  const ushort* Sc;
  Seg seg[3];
  int e0, e1;            // seg0: [0,e0), seg1: [e0,e1), seg2: [e1, ...)
};

template<int MT>
__global__ __launch_bounds__(256) void k_diffN(DiffA da){
  __shared__ ushort X[64][XP];
  int bx = blockIdx.x;
  Seg sg; int u;
  if (bx < da.e0){ sg = da.seg[0]; u = bx; }
  else if (bx < da.e1){ sg = da.seg[1]; u = bx - da.e0; }
  else { sg = da.seg[2]; u = bx - da.e1; }
  int t = threadIdx.x, b = t & 63, w = t >> 6;
  int r = t & 15, g = (t >> 4) & 3;

  if (sg.sm){
    // contiguous channel scan: src[(n)*64 + b]
    const ushort* src = sg.sm + (size_t)(sg.cs0 + u)*NN*64;
    for (int o8 = w; o8 < KD/8; o8 += 4){
      int n0 = o8*8;
      short8v pk;
      #pragma unroll
      for (int i = 0; i < 8; ++i){
        int n = n0 + i;
        pk[i] = (n < NN) ? (short)src[(size_t)n*64 + b] : (short)0;
      }
      *(short8v*)&X[b][n0] = pk;
    }
  } else {
    for (int idx = t; idx < 64*(KD/8); idx += 256){
      int bb2 = idx / (KD/8);
      int n0 = (idx - bb2*(KD/8))*8;
      #pragma unroll
      for (int i = 0; i < 8; ++i){
        int n = n0 + i;
        ushort us = 0;
        if (n < NN){
          us = f2bf(sg.sf[(size_t)bb2*NN + n]);
          sg.dm[(size_t)n*64 + bb2] = us;      // slot 0 (x channel)
        }
        X[bb2][n] = us;
      }
    }
  }
  __syncthreads();

  for (int m = 0; m < 4; ++m){
    const ushort* S = da.Sc + ((size_t)m*NPADR + (size_t)blockIdx.y*(MT*64))*KD;
    float4v acc[MT][4];
    #pragma unroll
    for (int i = 0; i < MT; ++i)
      #pragma unroll
      for (int q = 0; q < 4; ++q) acc[i][q] = (float4v){0.f,0.f,0.f,0.f};
    for (int kc = 0; kc < KD/32; ++kc){
      short8v a[MT], bbv[4];
      #pragma unroll
      for (int mt = 0; mt < MT; ++mt)
        a[mt] = *(const short8v*)&S[(size_t)((w*MT + mt)*16 + r)*KD + kc*32 + g*8];
      #pragma unroll
      for (int nt = 0; nt < 4; ++nt)
        bbv[nt] = *(const short8v*)&X[nt*16 + r][kc*32 + g*8];
      #pragma unroll
      for (int mt = 0; mt < MT; ++mt)
        #pragma unroll
        for (int nt = 0; nt < 4; ++nt)
          acc[mt][nt] = __builtin_amdgcn_mfma_f32_16x16x32_bf16(a[mt], bbv[nt], acc[mt][nt], 0, 0, 0);
    }
    // contiguous write region for this block's channel
    ushort* dst = sg.dm + (size_t)((1 + m)*sg.C + sg.cd0 + u)*NN*64;
    #pragma unroll
    for (int mt = 0; mt < MT; ++mt){
      int node0 = blockIdx.y*(MT*64) + (w*MT + mt)*16 + g*4;
      #pragma unroll
      for (int nt = 0; nt < 4; ++nt){
        int col = nt*16 + r;
        #pragma unroll
        for (int i = 0; i < 4; ++i){
          int n = node0 + i;
          if (n < NN) dst[(size_t)n*64 + col] = f2bf(acc[mt][nt][i]);
        }
      }
    }
  }
}

// ------------------------------------------- dual-descriptor W-GEMM (MFMA) ----
struct WgD {
  const ushort* mats; const ushort* Wt; const float* bias;
  float* h; float* uu;
  ushort* dstA; ushort* dstB;         // kk-major slot bases (dstB may be null)
  const float* Wfc; const float* bfc; float* outp;
  const float* xnext; ushort* xdst;   // optional next-x stage (MODE 1)
  int KPAD; int MODE;      // MODE 0: gate (O=128, rh+uu); 1: cand (O=64, h-update)
};

__global__ __launch_bounds__(256) void k_wg2(WgD d0, int n0, WgD d1){
  __shared__ ushort XT[64][XP];
  __shared__ float fcbuf[64];
  const bool first = (blockIdx.x < (unsigned)n0);
  WgD d = first ? d0 : d1;
  int n = first ? blockIdx.x : blockIdx.x - n0;
  int t = threadIdx.x, b = t & 63, w = t >> 6;
  int r = t & 15, g = (t >> 4) & 3;
  const int KPAD = d.KPAD;
  const int NST = (KPAD > 352) ? 2 : 1;
  const int KH  = (KPAD > 352) ? 320 : KPAD;
  const int OT  = (d.MODE == 0) ? 2 : 1;
  const bool fc = (d.MODE == 1) && (d.outp != nullptr);
  if (fc && t < 64) fcbuf[t] = 0.f;

  float4v acc[2][4];
  #pragma unroll
  for (int j = 0; j < 2; ++j)
    #pragma unroll
    for (int nt = 0; nt < 4; ++nt) acc[j][nt] = (float4v){0.f,0.f,0.f,0.f};

  for (int st = 0; st < NST; ++st){
    int kbase = st*KH;
    if (st) __syncthreads();
    for (int o8 = w; o8 < KH/8; o8 += 4){
      int k0 = o8*8;
      short8v pk;
      #pragma unroll
      for (int i = 0; i < 8; ++i)
        pk[i] = (short)d.mats[((size_t)(kbase + k0 + i)*NN + n)*64 + b];
      *(short8v*)&XT[b][k0] = pk;
    }
    __syncthreads();
    for (int kc = 0; kc < KH/32; ++kc){
      short8v a0, a1, bbv[4];
      a0 = *(const short8v*)&d.Wt[(size_t)(w*16 + r)*KPAD + kbase + kc*32 + g*8];
      if (OT == 2)
        a1 = *(const short8v*)&d.Wt[(size_t)((w + 4)*16 + r)*KPAD + kbase + kc*32 + g*8];
      #pragma unroll
      for (int nt = 0; nt < 4; ++nt)
        bbv[nt] = *(const short8v*)&XT[nt*16 + r][kc*32 + g*8];
      #pragma unroll
      for (int nt = 0; nt < 4; ++nt)
        acc[0][nt] = __builtin_amdgcn_mfma_f32_16x16x32_bf16(a0, bbv[nt], acc[0][nt], 0, 0, 0);
      if (OT == 2)
        #pragma unroll
        for (int nt = 0; nt < 4; ++nt)
          acc[1][nt] = __builtin_amdgcn_mfma_f32_16x16x32_bf16(a1, bbv[nt], acc[1][nt], 0, 0, 0);
    }
  }

  __syncthreads();                        // all XT reads done; reuse as out stage
  for (int j = 0; j < OT; ++j){
    #pragma unroll
    for (int nt = 0; nt < 4; ++nt){
      int b2 = nt*16 + r;
      float p = 0.f;
      #pragma unroll
      for (int i = 0; i < 4; ++i){
        int o = (w + 4*j)*16 + g*4 + i;
        float v = acc[j][nt][i] + d.bias[o];
        if (d.MODE == 0){
          float sg = 1.f/(1.f + expf(-v));
          if (o < 64){
            XT[o][b2] = f2bf(sg * d.h[(size_t)n*NODE + o*64 + b2]);
          } else {
            d.uu[(size_t)n*NODE + (o - 64)*64 + b2] = sg;
          }
        } else {
          float cv = tanhf(v);
          size_t idx = (size_t)n*NODE + o*64 + b2;
          float uv = d.uu[idx];
          float hn = uv*d.h[idx] + (1.f - uv)*cv;
          d.h[idx] = hn;
          XT[o][b2] = f2bf(hn);
          if (fc) p += hn * d.Wfc[o];
        }
      }
      if (fc) atomicAdd(&fcbuf[b2], p);
    }
  }
  __syncthreads();
  {                                        // coalesced copy-out of 64 kk-lines
    int o = t >> 2, q = (t & 3)*16;
    short8v v0 = *(short8v*)&XT[o][q];
    short8v v1 = *(short8v*)&XT[o][q + 8];
    ushort* dl = d.dstA + ((size_t)o*NN + n)*64 + q;
    *(short8v*)&dl[0] = v0;
    *(short8v*)&dl[8] = v1;
    if (d.dstB){
      ushort* dl2 = d.dstB + ((size_t)o*NN + n)*64 + q;
      *(short8v*)&dl2[0] = v0;
      *(short8v*)&dl2[8] = v1;
    }
  }
  if (d.MODE == 1){
    if (d.xnext && t < 64)
      d.xdst[(size_t)n*64 + t] = f2bf(d.xnext[(size_t)t*NN + n]);
    if (fc && t < 64)
      d.outp[(size_t)t*NN + n] = fcbuf[t] + d.bfc[0];
  }
}

// ----------------------------------------------------------------- host ----
extern "C" void kernel_launch(void* const* d_in, const int* in_sizes, int n_in,
                              void* d_out, int out_size, void* d_ws, size_t ws_size,
                              hipStream_t stream){
  const float* inp  = (const float*)d_in[0];
  const float* init = (const float*)d_in[1];
  const float* adj  = (const float*)d_in[2];
  const float* Wg0  = (const float*)d_in[3];
  const float* bg0  = (const float*)d_in[4];
  const float* Wc0  = (const float*)d_in[5];
  const float* bc0  = (const float*)d_in[6];
  const float* Wg1  = (const float*)d_in[7];
  const float* bg1  = (const float*)d_in[8];
  const float* Wc1  = (const float*)d_in[9];
  const float* bc1  = (const float*)d_in[10];
  const float* Wfc  = (const float*)d_in[11];
  const float* bfc  = (const float*)d_in[12];
  (void)in_sizes; (void)n_in; (void)out_size; (void)ws_size;

  char* p = (char*)d_ws;
  auto alloc = [&](size_t bytes) -> void* {
    void* q = (void*)p; p += (bytes + 255) & ~(size_t)255; return q;
  };
  ushort* Scomb  = (ushort*)alloc((size_t)4*NPADR*KD*2);
  float*  Sfp    = (float*)alloc((size_t)2*NN*NN*4);
  ushort* Wg0t   = (ushort*)alloc((size_t)128*KP0*2);
  ushort* Wc0t   = (ushort*)alloc((size_t)64*KP0*2);
  ushort* Wg1t   = (ushort*)alloc((size_t)128*KP1*2);
  ushort* Wc1t   = (ushort*)alloc((size_t)64*KP1*2);
  float*  rs     = (float*)alloc(512*4);
  float*  cs     = (float*)alloc(512*4);
  float*  h0     = (float*)alloc((size_t)NN*NODE*4);
  float*  h1     = (float*)alloc((size_t)NN*NODE*4);
  float*  uu0    = (float*)alloc((size_t)NN*NODE*4);
  float*  uu1    = (float*)alloc((size_t)NN*NODE*4);
  ushort* matsL0 = (ushort*)alloc((size_t)KP0*NN*64*2);
  ushort* matsL1 = (ushort*)alloc((size_t)KP1*NN*64*2);
  float* out = (float*)d_out;

  hipMemsetAsync(out, 0, (size_t)BB*NN*4, stream);
  // kk-major: only the contiguous pad tail kk in [325, 352) needs zeroing
  hipMemsetAsync(matsL0 + (size_t)325*NN*64, 0, (size_t)(KP0 - 325)*NN*64*2, stream);
  hipMemsetAsync(Scomb, 0, (size_t)4*NPADR*KD*2, stream);

  k_sums<<<NN, 256, 0, stream>>>(adj, rs, cs);
  k_setup2<<<SB2, 256, 0, stream>>>(adj, rs, cs, inp, init, Wg0, Wc0, Wg1, Wc1,
                                    Sfp, Scomb, Wg0t, Wc0t, Wg1t, Wc1t,
                                    h0, h1, matsL0, matsL1);
  k_s2<<<dim3(6, 2, 2), 256, 0, stream>>>(Sfp, Scomb);

  Seg segL0g  = { matsL0, nullptr, matsL0, 65, 0, 0 };      // full gate L0 (65 ch)
  Seg segL0c  = { matsL0, nullptr, matsL0, 65, 1, 1 };      // rh / h0 (64 ch)
  Seg segL1h1 = { matsL1, nullptr, matsL1, 128, 64, 64 };   // h1 / rh1 (64 ch)
  Seg segL1h0 = { matsL1, nullptr, matsL1, 128, 0, 0 };     // h0-part (64 ch)

  // priming: full L0-gate diffusion (x_0 + h0)
  { DiffA da = { Scomb, { segL0g, segL0g, segL0g }, 65, 65 };
    k_diffN<3><<<dim3(65, 2), 256, 0, stream>>>(da); }

  WgD wg_g0 = { matsL0, Wg0t, bg0, h0, uu0, matsL0 + (size_t)1*NN*64, nullptr,
                nullptr, nullptr, nullptr, nullptr, nullptr, KP0, 0 };
  WgD wg_c0 = { matsL0, Wc0t, bc0, h0, uu0, matsL0 + (size_t)1*NN*64, matsL1,
                nullptr, nullptr, nullptr, nullptr, nullptr, KP0, 1 };
  WgD wg_g1 = { matsL1, Wg1t, bg1, h1, uu1, matsL1 + (size_t)64*NN*64, nullptr,
                nullptr, nullptr, nullptr, nullptr, nullptr, KP1, 0 };

  k_wg2<<<NN, 256, 0, stream>>>(wg_g0, NN, wg_g0);        // wg L0-gate, t=0

  for (int t = 0; t < TT; ++t){
    // P2: L0-cand diff (rh) + L1-gate diff h1-part
    { DiffA da = { Scomb, { segL0c, segL1h1, segL0c }, 64, 128 };
      k_diffN<3><<<dim3(128, 2), 256, 0, stream>>>(da); }
    // P3: wg L0-cand -> h0_new
    k_wg2<<<NN, 256, 0, stream>>>(wg_c0, NN, wg_c0);
    // P4: L1-gate diff h0-part + next-L0-gate diff h0-part + x_{t+1} channel
    { Seg segX = { nullptr, inp + (size_t)(t + 1)*BB*NN, matsL0, 65, 0, 0 };
      DiffA da = { Scomb, { segL1h0, segL0c, segX }, 64, 128 };
      k_diffN<3><<<dim3(129, 2), 256, 0, stream>>>(da); }
    // P5: wg L1-gate -> rh1 + uu1
    k_wg2<<<NN, 256, 0, stream>>>(wg_g1, NN, wg_g1);
    // P6: L1-cand diff (rh1)
    { DiffA da = { Scomb, { segL1h1, segL1h1, segL1h1 }, 64, 64 };
      k_diffN<2><<<dim3(64, 3), 256, 0, stream>>>(da); }
    // P7: wg L1-cand (+fc)  [merged with next step's wg L0-gate]
    WgD wg_c1 = { matsL1, Wc1t, bc1, h1, uu1, matsL1 + (size_t)64*NN*64, nullptr,
                  Wfc, bfc, out + (size_t)(t + 1)*BB*NN,
                  (t + 1 < TT) ? inp + (size_t)(t + 1)*BB*NN : nullptr, matsL0,
                  KP1, 1 };
    if (t < TT - 1)
      k_wg2<<<2*NN, 256, 0, stream>>>(wg_c1, NN, wg_g0);
    else
      k_wg2<<<NN, 256, 0, stream>>>(wg_c1, NN, wg_c1);
  }
}

// Round 9
// 2128.624 us; speedup vs baseline: 5.2671x; 1.5408x over previous
//
#include <hip/hip_runtime.h>
#include <math.h>

#define NN    325
#define BB    64
#define TT    12
#define NODE  4096          // per-node stride of fp32 h/uu buffers: [n][c<64][b<64]
#define KD    352           // padded k-dim (nodes), 11*32
#define NPADR 384           // padded Scomb rows per matrix (24 tiles of 16)
#define XP    360           // LDS pitch
#define KP0   352           // mats kk count, layer 0 (5*65=325 used)
#define KP1   640           // mats kk count, layer 1 (5*128)
#define SB2   512           // setup2 grid
// mats layout (kk-major): mats[(kk*NN + n)*64 + b]

typedef unsigned short ushort;
typedef __attribute__((ext_vector_type(8))) short short8v;
typedef __attribute__((ext_vector_type(4))) short short4v;
typedef __attribute__((ext_vector_type(4))) float float4v;

static __device__ __forceinline__ ushort f2bf(float f){
  unsigned u = __builtin_bit_cast(unsigned, f);
  u += 0x7fffu + ((u >> 16) & 1u);          // RNE
  return (ushort)(u >> 16);
}

// ---------------------------------------------------------------- setup ----
__global__ void k_sums(const float* __restrict__ adj, float* __restrict__ rs,
                       float* __restrict__ cs){
  __shared__ float red[8];
  int j = blockIdx.x;
  int tid = threadIdx.x, gq = tid >> 6;
  float rv = 0.f, cv = 0.f;
  for (int k = tid; k < NN; k += 256){
    rv += adj[j*NN + k];
    cv += adj[k*NN + j];
  }
  #pragma unroll
  for (int o = 32; o > 0; o >>= 1){
    rv += __shfl_down(rv, o);
    cv += __shfl_down(cv, o);
  }
  if ((tid & 63) == 0){ red[gq] = rv; red[4 + gq] = cv; }
  __syncthreads();
  if (tid == 0){
    rs[j] = red[0]+red[1]+red[2]+red[3];
    cs[j] = red[4]+red[5]+red[6]+red[7];
  }
}

// merged: Sfp + Scomb slots 0,2 + Wt transposes + h/mats init
__global__ void k_setup2(const float* __restrict__ adj, const float* __restrict__ rs,
                         const float* __restrict__ cs, const float* __restrict__ inp,
                         const float* __restrict__ init,
                         const float* __restrict__ Wg0, const float* __restrict__ Wc0,
                         const float* __restrict__ Wg1, const float* __restrict__ Wc1,
                         float* __restrict__ Sfp, ushort* __restrict__ Scomb,
                         ushort* __restrict__ Wg0t, ushort* __restrict__ Wc0t,
                         ushort* __restrict__ Wg1t, ushort* __restrict__ Wc1t,
                         float* __restrict__ h0, float* __restrict__ h1,
                         ushort* __restrict__ matsL0, ushort* __restrict__ matsL1){
  int bx = blockIdx.x, t = threadIdx.x;
  if (bx < NN){                       // init task: node bx
    int n = bx, b = t & 63, cq = t >> 6;
    #pragma unroll
    for (int ii = 0; ii < 16; ++ii){
      int c = cq*16 + ii;
      float h0v = init[(size_t)(b*NN + n)*64 + c];
      float h1v = init[(size_t)BB*NN*64 + (size_t)(b*NN + n)*64 + c];
      h0[(size_t)n*NODE + c*64 + b] = h0v;
      h1[(size_t)n*NODE + c*64 + b] = h1v;
      matsL0[((size_t)(1 + c)*NN + n)*64 + b]  = f2bf(h0v);
      matsL1[((size_t)c*NN + n)*64 + b]        = f2bf(h0v);
      matsL1[((size_t)(64 + c)*NN + n)*64 + b] = f2bf(h1v);
    }
    if (t < 64)
      matsL0[(size_t)n*64 + t] = f2bf(inp[(size_t)t*NN + n]);
  }
  for (int idx = bx*256 + t; idx < 2*NN*NN; idx += SB2*256){
    int s = idx / (NN*NN), rem = idx - s*(NN*NN);
    int i = rem / NN, j = rem - i*NN;
    float v = s ? adj[i*NN + j]/cs[j] : adj[j*NN + i]/rs[j];
    Sfp[idx] = v;
    Scomb[(size_t)(2*s)*NPADR*KD + (size_t)i*KD + j] = f2bf(v);
  }
  // Wt[o][k], k = m*C + c, from W[(c*5+m)*O + o]; zero for k >= 5C
  {
    const float* Ws[4] = { Wg0, Wc0, Wg1, Wc1 };
    ushort* Wts[4]     = { Wg0t, Wc0t, Wg1t, Wc1t };
    const int Cs[4] = { 65, 65, 128, 128 };
    const int Os[4] = { 128, 64, 128, 64 };
    const int Kp[4] = { KP0, KP0, KP1, KP1 };
    for (int q = 0; q < 4; ++q){
      int total = Os[q]*Kp[q];
      for (int idx = bx*256 + t; idx < total; idx += SB2*256){
        int o = idx / Kp[q], k = idx - o*Kp[q];
        int m = k / Cs[q], c = k - m*Cs[q];
        Wts[q][idx] = f2bf(m < 5 ? Ws[q][(c*5 + m)*Os[q] + o] : 0.f);
      }
    }
  }
}

// Scomb slots 1,3 = 2*S_s^2 - I via MFMA (A = Scomb slot 2s bf16, X staged from Sfp)
__global__ __launch_bounds__(256) void k_s2(const float* __restrict__ Sfp,
                                            ushort* __restrict__ Scomb){
  __shared__ ushort X[64][XP];
  int jt = blockIdx.x, rh2 = blockIdx.y, s = blockIdx.z;
  int t = threadIdx.x, w = t >> 6, r = t & 15, g = (t >> 4) & 3;
  const float* S = Sfp + (size_t)s*NN*NN;
  for (int idx = t; idx < KD*8; idx += 256){
    int k = idx >> 3, j0 = (idx & 7)*8;
    #pragma unroll
    for (int i = 0; i < 8; ++i){
      int j = j0 + i, col = jt*64 + j;
      float v = (k < NN && col < NN) ? S[(size_t)k*NN + col] : 0.f;
      X[j][k] = f2bf(v);
    }
  }
  __syncthreads();
  const ushort* A = Scomb + (size_t)(2*s)*NPADR*KD + (size_t)(rh2*192)*KD;
  float4v acc[3][4];
  #pragma unroll
  for (int i = 0; i < 3; ++i)
    #pragma unroll
    for (int q = 0; q < 4; ++q) acc[i][q] = (float4v){0.f,0.f,0.f,0.f};
  for (int kc = 0; kc < KD/32; ++kc){
    short8v a[3], bbv[4];
    #pragma unroll
    for (int mt = 0; mt < 3; ++mt)
      a[mt] = *(const short8v*)&A[(size_t)((w*3 + mt)*16 + r)*KD + kc*32 + g*8];
    #pragma unroll
    for (int nt = 0; nt < 4; ++nt)
      bbv[nt] = *(const short8v*)&X[nt*16 + r][kc*32 + g*8];
    #pragma unroll
    for (int mt = 0; mt < 3; ++mt)
      #pragma unroll
      for (int nt = 0; nt < 4; ++nt)
        acc[mt][nt] = __builtin_amdgcn_mfma_f32_16x16x32_bf16(a[mt], bbv[nt], acc[mt][nt], 0, 0, 0);
  }
  ushort* dst = Scomb + (size_t)(2*s + 1)*NPADR*KD;
  #pragma unroll
  for (int mt = 0; mt < 3; ++mt){
    int node0 = rh2*192 + (w*3 + mt)*16 + g*4;
    #pragma unroll
    for (int nt = 0; nt < 4; ++nt){
      int col = nt*16 + r, jg = jt*64 + col;
      #pragma unroll
      for (int i = 0; i < 4; ++i){
        int n = node0 + i;
        if (n < NN && jg < NN)
          dst[(size_t)n*KD + jg] = f2bf(2.f*acc[mt][nt][i] - (n == jg ? 1.f : 0.f));
      }
    }
  }
}

// ----------------------------------------------- multi-segment diffusion ----
struct Seg {
  const ushort* sm;      // mats source channel base (or null -> sf)
  const float*  sf;      // fp32 [b*NN + n] source (x channel); also writes slot 0
  ushort* dm;
  int C, cs0, cd0;
};
struct DiffA {
  const ushort* Sc;
  Seg seg[3];
  int e0, e1;            // seg0: [0,e0), seg1: [e0,e1), seg2: [e1, ...)
};

// grid: x = channel unit, y = row-tile, z = m-pair (m = z*2 + {0,1})
template<int MT>
__global__ __launch_bounds__(256) void k_diffN(DiffA da){
  __shared__ ushort X[64][XP];
  int bx = blockIdx.x;
  Seg sg; int u;
  if (bx < da.e0){ sg = da.seg[0]; u = bx; }
  else if (bx < da.e1){ sg = da.seg[1]; u = bx - da.e0; }
  else { sg = da.seg[2]; u = bx - da.e1; }
  int t = threadIdx.x, w = t >> 6;
  int r = t & 15, g = (t >> 4) & 3;

  if (sg.sm){
    // deep-MLP vector stage: thread loads 11 x short8 (16B, 8 lines per wave-instr)
    const ushort* src = sg.sm + (size_t)(sg.cs0 + u)*NN*64;
    int nb = t >> 3, b0 = (t & 7)*8;
    const short8v vz = {0,0,0,0,0,0,0,0};
    short8v v[11];
    #pragma unroll
    for (int j = 0; j < 11; ++j){
      int n = j*32 + nb;
      v[j] = (n < NN) ? *(const short8v*)&src[(size_t)n*64 + b0] : vz;
    }
    #pragma unroll
    for (int j = 0; j < 11; ++j){
      int n = j*32 + nb;
      #pragma unroll
      for (int i = 0; i < 8; ++i) X[b0 + i][n] = (ushort)v[j][i];
    }
  } else {
    // fp32 x channel: scalar loads (independent, deep), + slot-0 writeback
    for (int j = 0; j < 22; ++j){
      int idx = j*256 + t;                 // 5632 = 64 b * 88 n4-groups
      int b = idx / 88, n4 = (idx - b*88)*4;
      ushort us[4];
      #pragma unroll
      for (int i = 0; i < 4; ++i)
        us[i] = (n4 + i < NN) ? f2bf(sg.sf[(size_t)b*NN + n4 + i]) : (ushort)0;
      short4v pk; pk[0]=(short)us[0]; pk[1]=(short)us[1]; pk[2]=(short)us[2]; pk[3]=(short)us[3];
      *(short4v*)&X[b][n4] = pk;
      #pragma unroll
      for (int i = 0; i < 4; ++i)
        if (n4 + i < NN) sg.dm[(size_t)(n4 + i)*64 + b] = us[i];
    }
  }
  __syncthreads();

  #pragma unroll
  for (int mi = 0; mi < 2; ++mi){
    int m = blockIdx.z*2 + mi;
    const ushort* S = da.Sc + ((size_t)m*NPADR + (size_t)blockIdx.y*(MT*64))*KD;
    float4v acc[MT][4];
    #pragma unroll
    for (int i = 0; i < MT; ++i)
      #pragma unroll
      for (int q = 0; q < 4; ++q) acc[i][q] = (float4v){0.f,0.f,0.f,0.f};
    for (int kc = 0; kc < KD/32; ++kc){
      short8v a[MT], bbv[4];
      #pragma unroll
      for (int mt = 0; mt < MT; ++mt)
        a[mt] = *(const short8v*)&S[(size_t)((w*MT + mt)*16 + r)*KD + kc*32 + g*8];
      #pragma unroll
      for (int nt = 0; nt < 4; ++nt)
        bbv[nt] = *(const short8v*)&X[nt*16 + r][kc*32 + g*8];
      #pragma unroll
      for (int mt = 0; mt < MT; ++mt)
        #pragma unroll
        for (int nt = 0; nt < 4; ++nt)
          acc[mt][nt] = __builtin_amdgcn_mfma_f32_16x16x32_bf16(a[mt], bbv[nt], acc[mt][nt], 0, 0, 0);
    }
    ushort* dst = sg.dm + (size_t)((1 + m)*sg.C + sg.cd0 + u)*NN*64;
    #pragma unroll
    for (int mt = 0; mt < MT; ++mt){
      int node0 = blockIdx.y*(MT*64) + (w*MT + mt)*16 + g*4;
      #pragma unroll
      for (int nt = 0; nt < 4; ++nt){
        int col = nt*16 + r;
        #pragma unroll
        for (int i = 0; i < 4; ++i){
          int n = node0 + i;
          if (n < NN) dst[(size_t)n*64 + col] = f2bf(acc[mt][nt][i]);
        }
      }
    }
  }
}

// ------------------------------------------- dual-descriptor W-GEMM (MFMA) ----
struct WgD {
  const ushort* mats; const ushort* Wt; const float* bias;
  float* h; float* uu;
  ushort* dstA; ushort* dstB;         // kk-major slot bases (dstB may be null)
  const float* Wfc; const float* bfc; float* outp;
  const float* xnext; ushort* xdst;   // optional next-x stage (MODE 1)
  int KPAD; int MODE;      // MODE 0: gate (o-tile = oy*64); 1: cand (h-update)
};

template<int KPAD>
static __device__ __forceinline__ void wg_body(
    const WgD& d, int n, int oy, ushort (*XT)[XP], float* fcbuf)
{
  constexpr int NST = (KPAD > 352) ? 2 : 1;
  constexpr int KH  = (KPAD > 352) ? 320 : KPAD;
  constexpr int NCH = KH/32;
  int t = threadIdx.x, w = t >> 6;
  int r = t & 15, g = (t >> 4) & 3;
  const bool fc = (d.MODE == 1) && (d.outp != nullptr);
  if (fc && t < 64) fcbuf[t] = 0.f;

  float4v acc[4];
  #pragma unroll
  for (int nt = 0; nt < 4; ++nt) acc[nt] = (float4v){0.f,0.f,0.f,0.f};

  int kk0 = t >> 3, b0 = (t & 7)*8;
  #pragma unroll
  for (int st = 0; st < NST; ++st){
    int kbase = st*KH;
    if (st) __syncthreads();
    short8v v[NCH];
    #pragma unroll
    for (int j = 0; j < NCH; ++j)
      v[j] = *(const short8v*)&d.mats[((size_t)(kbase + j*32 + kk0)*NN + n)*64 + b0];
    #pragma unroll
    for (int j = 0; j < NCH; ++j)
      #pragma unroll
      for (int i = 0; i < 8; ++i) XT[b0 + i][j*32 + kk0] = (ushort)v[j][i];
    __syncthreads();
    for (int kc = 0; kc < NCH; ++kc){
      short8v a0 = *(const short8v*)&d.Wt[(size_t)(oy*64 + w*16 + r)*KPAD + kbase + kc*32 + g*8];
      short8v bbv[4];
      #pragma unroll
      for (int nt = 0; nt < 4; ++nt)
        bbv[nt] = *(const short8v*)&XT[nt*16 + r][kc*32 + g*8];
      #pragma unroll
      for (int nt = 0; nt < 4; ++nt)
        acc[nt] = __builtin_amdgcn_mfma_f32_16x16x32_bf16(a0, bbv[nt], acc[nt], 0, 0, 0);
    }
  }

  __syncthreads();                        // all XT reads done; reuse as out stage
  #pragma unroll
  for (int nt = 0; nt < 4; ++nt){
    int b2 = nt*16 + r;
    float p = 0.f;
    #pragma unroll
    for (int i = 0; i < 4; ++i){
      int o = w*16 + g*4 + i;             // within o-tile
      float vv = acc[nt][i] + d.bias[oy*64 + o];
      if (d.MODE == 0){
        float sg = 1.f/(1.f + expf(-vv));
        if (oy == 0) XT[o][b2] = f2bf(sg * d.h[(size_t)n*NODE + o*64 + b2]);
        else         d.uu[(size_t)n*NODE + o*64 + b2] = sg;
      } else {
        float cv = tanhf(vv);
        size_t idx = (size_t)n*NODE + o*64 + b2;
        float uv = d.uu[idx];
        float hn = uv*d.h[idx] + (1.f - uv)*cv;
        d.h[idx] = hn;
        XT[o][b2] = f2bf(hn);
        if (fc) p += hn * d.Wfc[o];
      }
    }
    if (fc) atomicAdd(&fcbuf[b2], p);
  }
  __syncthreads();
  if (d.MODE == 1 || oy == 0){             // coalesced copy-out of 64 kk-lines
    int o = t >> 2, q = (t & 3)*16;
    short8v v0 = *(short8v*)&XT[o][q];
    short8v v1 = *(short8v*)&XT[o][q + 8];
    ushort* dl = d.dstA + ((size_t)o*NN + n)*64 + q;
    *(short8v*)&dl[0] = v0;
    *(short8v*)&dl[8] = v1;
    if (d.dstB){
      ushort* dl2 = d.dstB + ((size_t)o*NN + n)*64 + q;
      *(short8v*)&dl2[0] = v0;
      *(short8v*)&dl2[8] = v1;
    }
  }
  if (d.MODE == 1){
    if (d.xnext && t < 64)
      d.xdst[(size_t)n*64 + t] = f2bf(d.xnext[(size_t)t*NN + n]);
    if (fc && t < 64)
      d.outp[(size_t)t*NN + n] = fcbuf[t] + d.bfc[0];
  }
}

__global__ __launch_bounds__(256) void k_wg2(WgD d0, int n0, WgD d1){
  __shared__ ushort XT[64][XP];
  __shared__ float fcbuf[64];
  const bool first = (blockIdx.x < (unsigned)n0);
  WgD d = first ? d0 : d1;
  int n = first ? blockIdx.x : blockIdx.x - n0;
  int oy = blockIdx.y;
  if (d.MODE == 1 && oy) return;           // block-uniform early exit
  if (d.KPAD == 352) wg_body<352>(d, n, oy, XT, fcbuf);
  else               wg_body<640>(d, n, oy, XT, fcbuf);
}

// ----------------------------------------------------------------- host ----
extern "C" void kernel_launch(void* const* d_in, const int* in_sizes, int n_in,
                              void* d_out, int out_size, void* d_ws, size_t ws_size,
                              hipStream_t stream){
  const float* inp  = (const float*)d_in[0];
  const float* init = (const float*)d_in[1];
  const float* adj  = (const float*)d_in[2];
  const float* Wg0  = (const float*)d_in[3];
  const float* bg0  = (const float*)d_in[4];
  const float* Wc0  = (const float*)d_in[5];
  const float* bc0  = (const float*)d_in[6];
  const float* Wg1  = (const float*)d_in[7];
  const float* bg1  = (const float*)d_in[8];
  const float* Wc1  = (const float*)d_in[9];
  const float* bc1  = (const float*)d_in[10];
  const float* Wfc  = (const float*)d_in[11];
  const float* bfc  = (const float*)d_in[12];
  (void)in_sizes; (void)n_in; (void)out_size; (void)ws_size;

  char* p = (char*)d_ws;
  auto alloc = [&](size_t bytes) -> void* {
    void* q = (void*)p; p += (bytes + 255) & ~(size_t)255; return q;
  };
  ushort* Scomb  = (ushort*)alloc((size_t)4*NPADR*KD*2);
  float*  Sfp    = (float*)alloc((size_t)2*NN*NN*4);
  ushort* Wg0t   = (ushort*)alloc((size_t)128*KP0*2);
  ushort* Wc0t   = (ushort*)alloc((size_t)64*KP0*2);
  ushort* Wg1t   = (ushort*)alloc((size_t)128*KP1*2);
  ushort* Wc1t   = (ushort*)alloc((size_t)64*KP1*2);
  float*  rs     = (float*)alloc(512*4);
  float*  cs     = (float*)alloc(512*4);
  float*  h0     = (float*)alloc((size_t)NN*NODE*4);
  float*  h1     = (float*)alloc((size_t)NN*NODE*4);
  float*  uu0    = (float*)alloc((size_t)NN*NODE*4);
  float*  uu1    = (float*)alloc((size_t)NN*NODE*4);
  ushort* matsL0 = (ushort*)alloc((size_t)KP0*NN*64*2);
  ushort* matsL1 = (ushort*)alloc((size_t)KP1*NN*64*2);
  float* out = (float*)d_out;

  hipMemsetAsync(out, 0, (size_t)BB*NN*4, stream);
  hipMemsetAsync(matsL0 + (size_t)325*NN*64, 0, (size_t)(KP0 - 325)*NN*64*2, stream);
  hipMemsetAsync(Scomb, 0, (size_t)4*NPADR*KD*2, stream);

  k_sums<<<NN, 256, 0, stream>>>(adj, rs, cs);
  k_setup2<<<SB2, 256, 0, stream>>>(adj, rs, cs, inp, init, Wg0, Wc0, Wg1, Wc1,
                                    Sfp, Scomb, Wg0t, Wc0t, Wg1t, Wc1t,
                                    h0, h1, matsL0, matsL1);
  k_s2<<<dim3(6, 2, 2), 256, 0, stream>>>(Sfp, Scomb);

  Seg segL0g  = { matsL0, nullptr, matsL0, 65, 0, 0 };      // full gate L0 (65 ch)
  Seg segL0c  = { matsL0, nullptr, matsL0, 65, 1, 1 };      // rh / h0 (64 ch)
  Seg segL1h1 = { matsL1, nullptr, matsL1, 128, 64, 64 };   // h1 / rh1 (64 ch)
  Seg segL1h0 = { matsL1, nullptr, matsL1, 128, 0, 0 };     // h0-part (64 ch)

  // priming: full L0-gate diffusion (x_0 + h0)
  { DiffA da = { Scomb, { segL0g, segL0g, segL0g }, 65, 65 };
    k_diffN<3><<<dim3(65, 2, 2), 256, 0, stream>>>(da); }

  WgD wg_g0 = { matsL0, Wg0t, bg0, h0, uu0, matsL0 + (size_t)1*NN*64, nullptr,
                nullptr, nullptr, nullptr, nullptr, nullptr, KP0, 0 };
  WgD wg_c0 = { matsL0, Wc0t, bc0, h0, uu0, matsL0 + (size_t)1*NN*64, matsL1,
                nullptr, nullptr, nullptr, nullptr, nullptr, KP0, 1 };
  WgD wg_g1 = { matsL1, Wg1t, bg1, h1, uu1, matsL1 + (size_t)64*NN*64, nullptr,
                nullptr, nullptr, nullptr, nullptr, nullptr, KP1, 0 };

  k_wg2<<<dim3(NN, 2), 256, 0, stream>>>(wg_g0, NN, wg_g0);   // wg L0-gate, t=0

  for (int t = 0; t < TT; ++t){
    // P2: L0-cand diff (rh) + L1-gate diff h1-part
    { DiffA da = { Scomb, { segL0c, segL1h1, segL0c }, 64, 128 };
      k_diffN<3><<<dim3(128, 2, 2), 256, 0, stream>>>(da); }
    // P3: wg L0-cand -> h0_new
    k_wg2<<<dim3(NN, 1), 256, 0, stream>>>(wg_c0, NN, wg_c0);
    // P4: L1-gate diff h0-part + next-L0-gate diff h0-part + x_{t+1} channel
    { Seg segX = { nullptr, inp + (size_t)(t + 1)*BB*NN, matsL0, 65, 0, 0 };
      DiffA da = { Scomb, { segL1h0, segL0c, segX }, 64, 128 };
      k_diffN<3><<<dim3(129, 2, 2), 256, 0, stream>>>(da); }
    // P5: wg L1-gate -> rh1 + uu1
    k_wg2<<<dim3(NN, 2), 256, 0, stream>>>(wg_g1, NN, wg_g1);
    // P6: L1-cand diff (rh1)
    { DiffA da = { Scomb, { segL1h1, segL1h1, segL1h1 }, 64, 64 };
      k_diffN<2><<<dim3(64, 3, 2), 256, 0, stream>>>(da); }
    // P7: wg L1-cand (+fc)  [merged with next step's wg L0-gate]
    WgD wg_c1 = { matsL1, Wc1t, bc1, h1, uu1, matsL1 + (size_t)64*NN*64, nullptr,
                  Wfc, bfc, out + (size_t)(t + 1)*BB*NN,
                  (t + 1 < TT) ? inp + (size_t)(t + 1)*BB*NN : nullptr, matsL0,
                  KP1, 1 };
    if (t < TT - 1)
      k_wg2<<<dim3(2*NN, 2), 256, 0, stream>>>(wg_c1, NN, wg_g0);
    else
      k_wg2<<<dim3(NN, 1), 256, 0, stream>>>(wg_c1, NN, wg_c1);
  }
}

// Round 10
// 2014.535 us; speedup vs baseline: 5.5654x; 1.0566x over previous
//
#include <hip/hip_runtime.h>
#include <math.h>

#define NN    325
#define BB    64
#define TT    12
#define NODE  4096          // per-node stride of fp32 h/uu buffers: [n][c<64][b<64]
#define KD    352           // padded k-dim (nodes), 11*32
#define NPADR 384           // padded Scomb rows per matrix (24 tiles of 16)
#define XP    360           // LDS pitch
#define OBP   72            // out-stage pitch (ushorts, 144B rows, 16B aligned)
#define KP0   352           // mats kk count, layer 0 (5*65=325 used)
#define KP1   640           // mats kk count, layer 1 (5*128)
#define SB2   512           // setup2 grid
// mats layout (kk-major): mats[(kk*NN + n)*64 + b]

typedef unsigned short ushort;
typedef __attribute__((ext_vector_type(8))) short short8v;
typedef __attribute__((ext_vector_type(4))) short short4v;
typedef __attribute__((ext_vector_type(4))) float float4v;

static __device__ __forceinline__ ushort f2bf(float f){
  unsigned u = __builtin_bit_cast(unsigned, f);
  u += 0x7fffu + ((u >> 16) & 1u);          // RNE
  return (ushort)(u >> 16);
}

// ---------------------------------------------------------------- setup ----
__global__ void k_sums(const float* __restrict__ adj, float* __restrict__ rs,
                       float* __restrict__ cs){
  __shared__ float red[8];
  int j = blockIdx.x;
  int tid = threadIdx.x, gq = tid >> 6;
  float rv = 0.f, cv = 0.f;
  for (int k = tid; k < NN; k += 256){
    rv += adj[j*NN + k];
    cv += adj[k*NN + j];
  }
  #pragma unroll
  for (int o = 32; o > 0; o >>= 1){
    rv += __shfl_down(rv, o);
    cv += __shfl_down(cv, o);
  }
  if ((tid & 63) == 0){ red[gq] = rv; red[4 + gq] = cv; }
  __syncthreads();
  if (tid == 0){
    rs[j] = red[0]+red[1]+red[2]+red[3];
    cs[j] = red[4]+red[5]+red[6]+red[7];
  }
}

// merged: Sfp + Scomb slots 0,2 + Wt transposes + h/mats init
__global__ void k_setup2(const float* __restrict__ adj, const float* __restrict__ rs,
                         const float* __restrict__ cs, const float* __restrict__ inp,
                         const float* __restrict__ init,
                         const float* __restrict__ Wg0, const float* __restrict__ Wc0,
                         const float* __restrict__ Wg1, const float* __restrict__ Wc1,
                         float* __restrict__ Sfp, ushort* __restrict__ Scomb,
                         ushort* __restrict__ Wg0t, ushort* __restrict__ Wc0t,
                         ushort* __restrict__ Wg1t, ushort* __restrict__ Wc1t,
                         float* __restrict__ h0, float* __restrict__ h1,
                         ushort* __restrict__ matsL0, ushort* __restrict__ matsL1){
  int bx = blockIdx.x, t = threadIdx.x;
  if (bx < NN){                       // init task: node bx
    int n = bx, b = t & 63, cq = t >> 6;
    #pragma unroll
    for (int ii = 0; ii < 16; ++ii){
      int c = cq*16 + ii;
      float h0v = init[(size_t)(b*NN + n)*64 + c];
      float h1v = init[(size_t)BB*NN*64 + (size_t)(b*NN + n)*64 + c];
      h0[(size_t)n*NODE + c*64 + b] = h0v;
      h1[(size_t)n*NODE + c*64 + b] = h1v;
      matsL0[((size_t)(1 + c)*NN + n)*64 + b]  = f2bf(h0v);
      matsL1[((size_t)c*NN + n)*64 + b]        = f2bf(h0v);
      matsL1[((size_t)(64 + c)*NN + n)*64 + b] = f2bf(h1v);
    }
    if (t < 64)
      matsL0[(size_t)n*64 + t] = f2bf(inp[(size_t)t*NN + n]);
  }
  for (int idx = bx*256 + t; idx < 2*NN*NN; idx += SB2*256){
    int s = idx / (NN*NN), rem = idx - s*(NN*NN);
    int i = rem / NN, j = rem - i*NN;
    float v = s ? adj[i*NN + j]/cs[j] : adj[j*NN + i]/rs[j];
    Sfp[idx] = v;
    Scomb[(size_t)(2*s)*NPADR*KD + (size_t)i*KD + j] = f2bf(v);
  }
  // Wt[o][k], k = m*C + c, from W[(c*5+m)*O + o]; zero for k >= 5C
  {
    const float* Ws[4] = { Wg0, Wc0, Wg1, Wc1 };
    ushort* Wts[4]     = { Wg0t, Wc0t, Wg1t, Wc1t };
    const int Cs[4] = { 65, 65, 128, 128 };
    const int Os[4] = { 128, 64, 128, 64 };
    const int Kp[4] = { KP0, KP0, KP1, KP1 };
    for (int q = 0; q < 4; ++q){
      int total = Os[q]*Kp[q];
      for (int idx = bx*256 + t; idx < total; idx += SB2*256){
        int o = idx / Kp[q], k = idx - o*Kp[q];
        int m = k / Cs[q], c = k - m*Cs[q];
        Wts[q][idx] = f2bf(m < 5 ? Ws[q][(c*5 + m)*Os[q] + o] : 0.f);
      }
    }
  }
}

// Scomb slots 1,3 = 2*S_s^2 - I via MFMA (A = Scomb slot 2s bf16, X staged from Sfp)
__global__ __launch_bounds__(256) void k_s2(const float* __restrict__ Sfp,
                                            ushort* __restrict__ Scomb){
  __shared__ ushort X[64][XP];
  int jt = blockIdx.x, rh2 = blockIdx.y, s = blockIdx.z;
  int t = threadIdx.x, w = t >> 6, r = t & 15, g = (t >> 4) & 3;
  const float* S = Sfp + (size_t)s*NN*NN;
  for (int idx = t; idx < KD*8; idx += 256){
    int k = idx >> 3, j0 = (idx & 7)*8;
    #pragma unroll
    for (int i = 0; i < 8; ++i){
      int j = j0 + i, col = jt*64 + j;
      float v = (k < NN && col < NN) ? S[(size_t)k*NN + col] : 0.f;
      X[j][k] = f2bf(v);
    }
  }
  __syncthreads();
  const ushort* A = Scomb + (size_t)(2*s)*NPADR*KD + (size_t)(rh2*192)*KD;
  float4v acc[3][4];
  #pragma unroll
  for (int i = 0; i < 3; ++i)
    #pragma unroll
    for (int q = 0; q < 4; ++q) acc[i][q] = (float4v){0.f,0.f,0.f,0.f};
  for (int kc = 0; kc < KD/32; ++kc){
    short8v a[3], bbv[4];
    #pragma unroll
    for (int mt = 0; mt < 3; ++mt)
      a[mt] = *(const short8v*)&A[(size_t)((w*3 + mt)*16 + r)*KD + kc*32 + g*8];
    #pragma unroll
    for (int nt = 0; nt < 4; ++nt)
      bbv[nt] = *(const short8v*)&X[nt*16 + r][kc*32 + g*8];
    #pragma unroll
    for (int mt = 0; mt < 3; ++mt)
      #pragma unroll
      for (int nt = 0; nt < 4; ++nt)
        acc[mt][nt] = __builtin_amdgcn_mfma_f32_16x16x32_bf16(a[mt], bbv[nt], acc[mt][nt], 0, 0, 0);
  }
  ushort* dst = Scomb + (size_t)(2*s + 1)*NPADR*KD;
  #pragma unroll
  for (int mt = 0; mt < 3; ++mt){
    int node0 = rh2*192 + (w*3 + mt)*16 + g*4;
    #pragma unroll
    for (int nt = 0; nt < 4; ++nt){
      int col = nt*16 + r, jg = jt*64 + col;
      #pragma unroll
      for (int i = 0; i < 4; ++i){
        int n = node0 + i;
        if (n < NN && jg < NN)
          dst[(size_t)n*KD + jg] = f2bf(2.f*acc[mt][nt][i] - (n == jg ? 1.f : 0.f));
      }
    }
  }
}

// ----------------------------------------------- multi-segment diffusion ----
struct Seg {
  const ushort* sm;      // mats source channel base (or null -> sf)
  const float*  sf;      // fp32 [b*NN + n] source (x channel); also writes slot 0
  ushort* dm;
  int C, cs0, cd0;
};
struct DiffA {
  const ushort* Sc;
  Seg seg[3];
  int e0, e1;            // seg0: [0,e0), seg1: [e0,e1), seg2: [e1, ...)
};

// grid: x = channel unit, y = row-half (192 rows), z = m (one matrix per block)
__global__ __launch_bounds__(256, 3) void k_diffN(DiffA da){
  __shared__ ushort X[64][XP];
  ushort (*OB)[OBP] = (ushort (*)[OBP])&X[0][0];   // out-stage overlay (27.6 KB)
  int bx = blockIdx.x;
  Seg sg; int u;
  if (bx < da.e0){ sg = da.seg[0]; u = bx; }
  else if (bx < da.e1){ sg = da.seg[1]; u = bx - da.e0; }
  else { sg = da.seg[2]; u = bx - da.e1; }
  int t = threadIdx.x, w = t >> 6;
  int r = t & 15, g = (t >> 4) & 3;
  const int m = blockIdx.z;

  if (sg.sm){
    // deep-MLP vector stage: thread loads 11 x short8 (16B, 8 lines per wave-instr)
    const ushort* src = sg.sm + (size_t)(sg.cs0 + u)*NN*64;
    int nb = t >> 3, b0 = (t & 7)*8;
    const short8v vz = {0,0,0,0,0,0,0,0};
    short8v v[11];
    #pragma unroll
    for (int j = 0; j < 11; ++j){
      int n = j*32 + nb;
      v[j] = (n < NN) ? *(const short8v*)&src[(size_t)n*64 + b0] : vz;
    }
    #pragma unroll
    for (int j = 0; j < 11; ++j){
      int n = j*32 + nb;
      #pragma unroll
      for (int i = 0; i < 8; ++i) X[b0 + i][n] = (ushort)v[j][i];
    }
  } else {
    // fp32 x channel: scalar loads (independent, deep), + slot-0 writeback
    for (int j = 0; j < 22; ++j){
      int idx = j*256 + t;                 // 5632 = 64 b * 88 n4-groups
      int b = idx / 88, n4 = (idx - b*88)*4;
      ushort us[4];
      #pragma unroll
      for (int i = 0; i < 4; ++i)
        us[i] = (n4 + i < NN) ? f2bf(sg.sf[(size_t)b*NN + n4 + i]) : (ushort)0;
      short4v pk; pk[0]=(short)us[0]; pk[1]=(short)us[1]; pk[2]=(short)us[2]; pk[3]=(short)us[3];
      *(short4v*)&X[b][n4] = pk;
      #pragma unroll
      for (int i = 0; i < 4; ++i)
        if (n4 + i < NN) sg.dm[(size_t)(n4 + i)*64 + b] = us[i];
    }
  }
  __syncthreads();

  const ushort* S = da.Sc + ((size_t)m*NPADR + (size_t)blockIdx.y*192)*KD;
  float4v acc[3][4];
  #pragma unroll
  for (int i = 0; i < 3; ++i)
    #pragma unroll
    for (int q = 0; q < 4; ++q) acc[i][q] = (float4v){0.f,0.f,0.f,0.f};
  for (int kc = 0; kc < KD/32; ++kc){
    short8v a[3], bbv[4];
    #pragma unroll
    for (int mt = 0; mt < 3; ++mt)
      a[mt] = *(const short8v*)&S[(size_t)((w*3 + mt)*16 + r)*KD + kc*32 + g*8];
    #pragma unroll
    for (int nt = 0; nt < 4; ++nt)
      bbv[nt] = *(const short8v*)&X[nt*16 + r][kc*32 + g*8];
    #pragma unroll
    for (int mt = 0; mt < 3; ++mt)
      #pragma unroll
      for (int nt = 0; nt < 4; ++nt)
        acc[mt][nt] = __builtin_amdgcn_mfma_f32_16x16x32_bf16(a[mt], bbv[nt], acc[mt][nt], 0, 0, 0);
  }

  __syncthreads();                        // all waves done reading X -> reuse as OB
  #pragma unroll
  for (int mt = 0; mt < 3; ++mt){
    int lr0 = (w*3 + mt)*16 + g*4;        // local row (within 192-row half)
    #pragma unroll
    for (int nt = 0; nt < 4; ++nt){
      int col = nt*16 + r;
      #pragma unroll
      for (int i = 0; i < 4; ++i)
        OB[lr0 + i][col] = f2bf(acc[mt][nt][i]);
    }
  }
  __syncthreads();
  // coalesced copy-out: full 128B lines (8 lanes x 16B per row)
  {
    ushort* dst = sg.dm + (size_t)((1 + m)*sg.C + sg.cd0 + u)*NN*64;
    int n0 = blockIdx.y*192;
    int lr = t >> 3, q = (t & 7)*8;
    #pragma unroll
    for (int it = 0; it < 6; ++it){
      int row = it*32 + lr;
      int n = n0 + row;
      if (n < NN)
        *(short8v*)&dst[(size_t)n*64 + q] = *(short8v*)&OB[row][q];
    }
  }
}

// ------------------------------------------- dual-descriptor W-GEMM (MFMA) ----
struct WgD {
  const ushort* mats; const ushort* Wt; const float* bias;
  float* h; float* uu;
  ushort* dstA; ushort* dstB;         // kk-major slot bases (dstB may be null)
  const float* Wfc; const float* bfc; float* outp;
  const float* xnext; ushort* xdst;   // optional next-x stage (MODE 1)
  int KPAD; int MODE;      // MODE 0: gate (o-tile = oy*64); 1: cand (h-update)
};

template<int KPAD>
static __device__ __forceinline__ void wg_body(
    const WgD& d, int n, int oy, ushort (*XT)[XP], float* fcbuf)
{
  constexpr int NST = (KPAD > 352) ? 2 : 1;
  constexpr int KH  = (KPAD > 352) ? 320 : KPAD;
  constexpr int NCH = KH/32;
  int t = threadIdx.x, w = t >> 6;
  int r = t & 15, g = (t >> 4) & 3;
  const bool fc = (d.MODE == 1) && (d.outp != nullptr);
  if (fc && t < 64) fcbuf[t] = 0.f;

  float4v acc[4];
  #pragma unroll
  for (int nt = 0; nt < 4; ++nt) acc[nt] = (float4v){0.f,0.f,0.f,0.f};

  int kk0 = t >> 3, b0 = (t & 7)*8;
  #pragma unroll
  for (int st = 0; st < NST; ++st){
    int kbase = st*KH;
    if (st) __syncthreads();
    short8v v[NCH];
    #pragma unroll
    for (int j = 0; j < NCH; ++j)
      v[j] = *(const short8v*)&d.mats[((size_t)(kbase + j*32 + kk0)*NN + n)*64 + b0];
    #pragma unroll
    for (int j = 0; j < NCH; ++j)
      #pragma unroll
      for (int i = 0; i < 8; ++i) XT[b0 + i][j*32 + kk0] = (ushort)v[j][i];
    __syncthreads();
    for (int kc = 0; kc < NCH; ++kc){
      short8v a0 = *(const short8v*)&d.Wt[(size_t)(oy*64 + w*16 + r)*KPAD + kbase + kc*32 + g*8];
      short8v bbv[4];
      #pragma unroll
      for (int nt = 0; nt < 4; ++nt)
        bbv[nt] = *(const short8v*)&XT[nt*16 + r][kc*32 + g*8];
      #pragma unroll
      for (int nt = 0; nt < 4; ++nt)
        acc[nt] = __builtin_amdgcn_mfma_f32_16x16x32_bf16(a0, bbv[nt], acc[nt], 0, 0, 0);
    }
  }

  __syncthreads();                        // all XT reads done; reuse as out stage
  #pragma unroll
  for (int nt = 0; nt < 4; ++nt){
    int b2 = nt*16 + r;
    float p = 0.f;
    #pragma unroll
    for (int i = 0; i < 4; ++i){
      int o = w*16 + g*4 + i;             // within o-tile
      float vv = acc[nt][i] + d.bias[oy*64 + o];
      if (d.MODE == 0){
        float sg = 1.f/(1.f + expf(-vv));
        if (oy == 0) XT[o][b2] = f2bf(sg * d.h[(size_t)n*NODE + o*64 + b2]);
        else         d.uu[(size_t)n*NODE + o*64 + b2] = sg;
      } else {
        float cv = tanhf(vv);
        size_t idx = (size_t)n*NODE + o*64 + b2;
        float uv = d.uu[idx];
        float hn = uv*d.h[idx] + (1.f - uv)*cv;
        d.h[idx] = hn;
        XT[o][b2] = f2bf(hn);
        if (fc) p += hn * d.Wfc[o];
      }
    }
    if (fc) atomicAdd(&fcbuf[b2], p);
  }
  __syncthreads();
  if (d.MODE == 1 || oy == 0){             // coalesced copy-out of 64 kk-lines
    int o = t >> 2, q = (t & 3)*16;
    short8v v0 = *(short8v*)&XT[o][q];
    short8v v1 = *(short8v*)&XT[o][q + 8];
    ushort* dl = d.dstA + ((size_t)o*NN + n)*64 + q;
    *(short8v*)&dl[0] = v0;
    *(short8v*)&dl[8] = v1;
    if (d.dstB){
      ushort* dl2 = d.dstB + ((size_t)o*NN + n)*64 + q;
      *(short8v*)&dl2[0] = v0;
      *(short8v*)&dl2[8] = v1;
    }
  }
  if (d.MODE == 1){
    if (d.xnext && t < 64)
      d.xdst[(size_t)n*64 + t] = f2bf(d.xnext[(size_t)t*NN + n]);
    if (fc && t < 64)
      d.outp[(size_t)t*NN + n] = fcbuf[t] + d.bfc[0];
  }
}

__global__ __launch_bounds__(256) void k_wg2(WgD d0, int n0, WgD d1){
  __shared__ ushort XT[64][XP];
  __shared__ float fcbuf[64];
  const bool first = (blockIdx.x < (unsigned)n0);
  WgD d = first ? d0 : d1;
  int n = first ? blockIdx.x : blockIdx.x - n0;
  int oy = blockIdx.y;
  if (d.MODE == 1 && oy) return;           // block-uniform early exit
  if (d.KPAD == 352) wg_body<352>(d, n, oy, XT, fcbuf);
  else               wg_body<640>(d, n, oy, XT, fcbuf);
}

// ----------------------------------------------------------------- host ----
extern "C" void kernel_launch(void* const* d_in, const int* in_sizes, int n_in,
                              void* d_out, int out_size, void* d_ws, size_t ws_size,
                              hipStream_t stream){
  const float* inp  = (const float*)d_in[0];
  const float* init = (const float*)d_in[1];
  const float* adj  = (const float*)d_in[2];
  const float* Wg0  = (const float*)d_in[3];
  const float* bg0  = (const float*)d_in[4];
  const float* Wc0  = (const float*)d_in[5];
  const float* bc0  = (const float*)d_in[6];
  const float* Wg1  = (const float*)d_in[7];
  const float* bg1  = (const float*)d_in[8];
  const float* Wc1  = (const float*)d_in[9];
  const float* bc1  = (const float*)d_in[10];
  const float* Wfc  = (const float*)d_in[11];
  const float* bfc  = (const float*)d_in[12];
  (void)in_sizes; (void)n_in; (void)out_size; (void)ws_size;

  char* p = (char*)d_ws;
  auto alloc = [&](size_t bytes) -> void* {
    void* q = (void*)p; p += (bytes + 255) & ~(size_t)255; return q;
  };
  ushort* Scomb  = (ushort*)alloc((size_t)4*NPADR*KD*2);
  float*  Sfp    = (float*)alloc((size_t)2*NN*NN*4);
  ushort* Wg0t   = (ushort*)alloc((size_t)128*KP0*2);
  ushort* Wc0t   = (ushort*)alloc((size_t)64*KP0*2);
  ushort* Wg1t   = (ushort*)alloc((size_t)128*KP1*2);
  ushort* Wc1t   = (ushort*)alloc((size_t)64*KP1*2);
  float*  rs     = (float*)alloc(512*4);
  float*  cs     = (float*)alloc(512*4);
  float*  h0     = (float*)alloc((size_t)NN*NODE*4);
  float*  h1     = (float*)alloc((size_t)NN*NODE*4);
  float*  uu0    = (float*)alloc((size_t)NN*NODE*4);
  float*  uu1    = (float*)alloc((size_t)NN*NODE*4);
  ushort* matsL0 = (ushort*)alloc((size_t)KP0*NN*64*2);
  ushort* matsL1 = (ushort*)alloc((size_t)KP1*NN*64*2);
  float* out = (float*)d_out;

  hipMemsetAsync(out, 0, (size_t)BB*NN*4, stream);
  hipMemsetAsync(matsL0 + (size_t)325*NN*64, 0, (size_t)(KP0 - 325)*NN*64*2, stream);
  hipMemsetAsync(Scomb, 0, (size_t)4*NPADR*KD*2, stream);

  k_sums<<<NN, 256, 0, stream>>>(adj, rs, cs);
  k_setup2<<<SB2, 256, 0, stream>>>(adj, rs, cs, inp, init, Wg0, Wc0, Wg1, Wc1,
                                    Sfp, Scomb, Wg0t, Wc0t, Wg1t, Wc1t,
                                    h0, h1, matsL0, matsL1);
  k_s2<<<dim3(6, 2, 2), 256, 0, stream>>>(Sfp, Scomb);

  Seg segL0g  = { matsL0, nullptr, matsL0, 65, 0, 0 };      // full gate L0 (65 ch)
  Seg segL0c  = { matsL0, nullptr, matsL0, 65, 1, 1 };      // rh / h0 (64 ch)
  Seg segL1h1 = { matsL1, nullptr, matsL1, 128, 64, 64 };   // h1 / rh1 (64 ch)
  Seg segL1h0 = { matsL1, nullptr, matsL1, 128, 0, 0 };     // h0-part (64 ch)

  // priming: full L0-gate diffusion (x_0 + h0)
  { DiffA da = { Scomb, { segL0g, segL0g, segL0g }, 65, 65 };
    k_diffN<<<dim3(65, 2, 4), 256, 0, stream>>>(da); }

  WgD wg_g0 = { matsL0, Wg0t, bg0, h0, uu0, matsL0 + (size_t)1*NN*64, nullptr,
                nullptr, nullptr, nullptr, nullptr, nullptr, KP0, 0 };
  WgD wg_c0 = { matsL0, Wc0t, bc0, h0, uu0, matsL0 + (size_t)1*NN*64, matsL1,
                nullptr, nullptr, nullptr, nullptr, nullptr, KP0, 1 };
  WgD wg_g1 = { matsL1, Wg1t, bg1, h1, uu1, matsL1 + (size_t)64*NN*64, nullptr,
                nullptr, nullptr, nullptr, nullptr, nullptr, KP1, 0 };

  k_wg2<<<dim3(NN, 2), 256, 0, stream>>>(wg_g0, NN, wg_g0);   // wg L0-gate, t=0

  for (int t = 0; t < TT; ++t){
    // P2: L0-cand diff (rh) + L1-gate diff h1-part
    { DiffA da = { Scomb, { segL0c, segL1h1, segL0c }, 64, 128 };
      k_diffN<<<dim3(128, 2, 4), 256, 0, stream>>>(da); }
    // P3: wg L0-cand -> h0_new
    k_wg2<<<dim3(NN, 1), 256, 0, stream>>>(wg_c0, NN, wg_c0);
    // P4: L1-gate diff h0-part + next-L0-gate diff h0-part + x_{t+1} channel
    { Seg segX = { nullptr, inp + (size_t)(t + 1)*BB*NN, matsL0, 65, 0, 0 };
      DiffA da = { Scomb, { segL1h0, segL0c, segX }, 64, 128 };
      k_diffN<<<dim3(129, 2, 4), 256, 0, stream>>>(da); }
    // P5: wg L1-gate -> rh1 + uu1
    k_wg2<<<dim3(NN, 2), 256, 0, stream>>>(wg_g1, NN, wg_g1);
    // P6: L1-cand diff (rh1)
    { DiffA da = { Scomb, { segL1h1, segL1h1, segL1h1 }, 64, 64 };
      k_diffN<<<dim3(64, 2, 4), 256, 0, stream>>>(da); }
    // P7: wg L1-cand (+fc)  [merged with next step's wg L0-gate]
    WgD wg_c1 = { matsL1, Wc1t, bc1, h1, uu1, matsL1 + (size_t)64*NN*64, nullptr,
                  Wfc, bfc, out + (size_t)(t + 1)*BB*NN,
                  (t + 1 < TT) ? inp + (size_t)(t + 1)*BB*NN : nullptr, matsL0,
                  KP1, 1 };
    if (t < TT - 1)
      k_wg2<<<dim3(2*NN, 2), 256, 0, stream>>>(wg_c1, NN, wg_g0);
    else
      k_wg2<<<dim3(NN, 1), 256, 0, stream>>>(wg_c1, NN, wg_c1);
  }
}

// Round 11
// 1676.034 us; speedup vs baseline: 6.6894x; 1.2020x over previous
//
#include <hip/hip_runtime.h>
#include <math.h>

#define NN    325
#define BB    64
#define TT    12
#define NODE  4096          // per-node stride of fp32 h/uu buffers: [n][c<64][b<64]
#define KD    352           // padded k-dim (nodes), 11*32
#define NPADR 384           // padded Scomb rows per matrix (24 tiles of 16)
#define XP    360           // LDS pitch
#define OBP   72            // out-stage pitch (ushorts)
#define KP0   352           // mats kk count, layer 0 (5*65=325 used)
#define KP1   640           // mats kk count, layer 1 (5*128)
#define SB2   512           // setup2 grid
// mats layout (kk-major): mats[(kk*NN + n)*64 + b]
// LDS tile swizzle: element (row,col) stored at col ^ (((row>>3)&3)<<3)

typedef unsigned short ushort;
typedef __attribute__((ext_vector_type(8))) short short8v;
typedef __attribute__((ext_vector_type(4))) short short4v;
typedef __attribute__((ext_vector_type(4))) float float4v;

static __device__ __forceinline__ ushort f2bf(float f){
  unsigned u = __builtin_bit_cast(unsigned, f);
  u += 0x7fffu + ((u >> 16) & 1u);          // RNE
  return (ushort)(u >> 16);
}

// ---------------------------------------------------------------- setup ----
__global__ void k_sums(const float* __restrict__ adj, float* __restrict__ rs,
                       float* __restrict__ cs){
  __shared__ float red[8];
  int j = blockIdx.x;
  int tid = threadIdx.x, gq = tid >> 6;
  float rv = 0.f, cv = 0.f;
  for (int k = tid; k < NN; k += 256){
    rv += adj[j*NN + k];
    cv += adj[k*NN + j];
  }
  #pragma unroll
  for (int o = 32; o > 0; o >>= 1){
    rv += __shfl_down(rv, o);
    cv += __shfl_down(cv, o);
  }
  if ((tid & 63) == 0){ red[gq] = rv; red[4 + gq] = cv; }
  __syncthreads();
  if (tid == 0){
    rs[j] = red[0]+red[1]+red[2]+red[3];
    cs[j] = red[4]+red[5]+red[6]+red[7];
  }
}

// merged: Sfp + Scomb slots 0,2 + Wt transposes + h/mats init
__global__ void k_setup2(const float* __restrict__ adj, const float* __restrict__ rs,
                         const float* __restrict__ cs, const float* __restrict__ inp,
                         const float* __restrict__ init,
                         const float* __restrict__ Wg0, const float* __restrict__ Wc0,
                         const float* __restrict__ Wg1, const float* __restrict__ Wc1,
                         float* __restrict__ Sfp, ushort* __restrict__ Scomb,
                         ushort* __restrict__ Wg0t, ushort* __restrict__ Wc0t,
                         ushort* __restrict__ Wg1t, ushort* __restrict__ Wc1t,
                         float* __restrict__ h0, float* __restrict__ h1,
                         ushort* __restrict__ matsL0, ushort* __restrict__ matsL1){
  int bx = blockIdx.x, t = threadIdx.x;
  if (bx < NN){                       // init task: node bx
    int n = bx, b = t & 63, cq = t >> 6;
    #pragma unroll
    for (int ii = 0; ii < 16; ++ii){
      int c = cq*16 + ii;
      float h0v = init[(size_t)(b*NN + n)*64 + c];
      float h1v = init[(size_t)BB*NN*64 + (size_t)(b*NN + n)*64 + c];
      h0[(size_t)n*NODE + c*64 + b] = h0v;
      h1[(size_t)n*NODE + c*64 + b] = h1v;
      matsL0[((size_t)(1 + c)*NN + n)*64 + b]  = f2bf(h0v);
      matsL1[((size_t)c*NN + n)*64 + b]        = f2bf(h0v);
      matsL1[((size_t)(64 + c)*NN + n)*64 + b] = f2bf(h1v);
    }
    if (t < 64)
      matsL0[(size_t)n*64 + t] = f2bf(inp[(size_t)t*NN + n]);
  }
  for (int idx = bx*256 + t; idx < 2*NN*NN; idx += SB2*256){
    int s = idx / (NN*NN), rem = idx - s*(NN*NN);
    int i = rem / NN, j = rem - i*NN;
    float v = s ? adj[i*NN + j]/cs[j] : adj[j*NN + i]/rs[j];
    Sfp[idx] = v;
    Scomb[(size_t)(2*s)*NPADR*KD + (size_t)i*KD + j] = f2bf(v);
  }
  // Wt[o][k], k = m*C + c, from W[(c*5+m)*O + o]; zero for k >= 5C
  {
    const float* Ws[4] = { Wg0, Wc0, Wg1, Wc1 };
    ushort* Wts[4]     = { Wg0t, Wc0t, Wg1t, Wc1t };
    const int Cs[4] = { 65, 65, 128, 128 };
    const int Os[4] = { 128, 64, 128, 64 };
    const int Kp[4] = { KP0, KP0, KP1, KP1 };
    for (int q = 0; q < 4; ++q){
      int total = Os[q]*Kp[q];
      for (int idx = bx*256 + t; idx < total; idx += SB2*256){
        int o = idx / Kp[q], k = idx - o*Kp[q];
        int m = k / Cs[q], c = k - m*Cs[q];
        Wts[q][idx] = f2bf(m < 5 ? Ws[q][(c*5 + m)*Os[q] + o] : 0.f);
      }
    }
  }
}

// Scomb slots 1,3 = 2*S_s^2 - I via MFMA (A = Scomb slot 2s bf16, X staged from Sfp)
__global__ __launch_bounds__(256) void k_s2(const float* __restrict__ Sfp,
                                            ushort* __restrict__ Scomb){
  __shared__ ushort X[64][XP];
  int jt = blockIdx.x, rh2 = blockIdx.y, s = blockIdx.z;
  int t = threadIdx.x, w = t >> 6, r = t & 15, g = (t >> 4) & 3;
  const float* S = Sfp + (size_t)s*NN*NN;
  for (int idx = t; idx < KD*8; idx += 256){
    int k = idx >> 3, j0 = (idx & 7)*8;
    #pragma unroll
    for (int i = 0; i < 8; ++i){
      int j = j0 + i, col = jt*64 + j;
      float v = (k < NN && col < NN) ? S[(size_t)k*NN + col] : 0.f;
      X[j][k] = f2bf(v);
    }
  }
  __syncthreads();
  const ushort* A = Scomb + (size_t)(2*s)*NPADR*KD + (size_t)(rh2*192)*KD;
  float4v acc[3][4];
  #pragma unroll
  for (int i = 0; i < 3; ++i)
    #pragma unroll
    for (int q = 0; q < 4; ++q) acc[i][q] = (float4v){0.f,0.f,0.f,0.f};
  for (int kc = 0; kc < KD/32; ++kc){
    short8v a[3], bbv[4];
    #pragma unroll
    for (int mt = 0; mt < 3; ++mt)
      a[mt] = *(const short8v*)&A[(size_t)((w*3 + mt)*16 + r)*KD + kc*32 + g*8];
    #pragma unroll
    for (int nt = 0; nt < 4; ++nt)
      bbv[nt] = *(const short8v*)&X[nt*16 + r][kc*32 + g*8];
    #pragma unroll
    for (int mt = 0; mt < 3; ++mt)
      #pragma unroll
      for (int nt = 0; nt < 4; ++nt)
        acc[mt][nt] = __builtin_amdgcn_mfma_f32_16x16x32_bf16(a[mt], bbv[nt], acc[mt][nt], 0, 0, 0);
  }
  ushort* dst = Scomb + (size_t)(2*s + 1)*NPADR*KD;
  #pragma unroll
  for (int mt = 0; mt < 3; ++mt){
    int node0 = rh2*192 + (w*3 + mt)*16 + g*4;
    #pragma unroll
    for (int nt = 0; nt < 4; ++nt){
      int col = nt*16 + r, jg = jt*64 + col;
      #pragma unroll
      for (int i = 0; i < 4; ++i){
        int n = node0 + i;
        if (n < NN && jg < NN)
          dst[(size_t)n*KD + jg] = f2bf(2.f*acc[mt][nt][i] - (n == jg ? 1.f : 0.f));
      }
    }
  }
}

// ----------------------------------------------- multi-segment diffusion ----
struct Seg {
  const ushort* sm;      // mats source channel base (or null -> sf)
  const float*  sf;      // fp32 [b*NN + n] source (x channel); also writes slot 0
  ushort* dm;
  int C, cs0, cd0;
};
struct DiffA {
  const ushort* Sc;
  Seg seg[3];
  int e0, e1, nch;       // seg0: [0,e0), seg1: [e0,e1), seg2: [e1,nch)
};

// 1D grid, XCD-aware decomposition: lin = (cu/8)*64 + sub*8 + (cu%8).
// All 8 sub-blocks (y=sub>>2, m=sub&3) of channel cu share lin%8 -> same XCD.
__global__ __launch_bounds__(256, 3) void k_diffN(DiffA da){
  __shared__ ushort X[64][XP];
  ushort (*OB)[OBP] = (ushort (*)[OBP])&X[0][0];   // out-stage overlay
  int lin = blockIdx.x;
  int cu = (lin >> 6)*8 + (lin & 7);
  if (cu >= da.nch) return;
  int sub = (lin >> 3) & 7;
  const int y = sub >> 2, m = sub & 3;
  Seg sg; int u;
  if (cu < da.e0){ sg = da.seg[0]; u = cu; }
  else if (cu < da.e1){ sg = da.seg[1]; u = cu - da.e0; }
  else { sg = da.seg[2]; u = cu - da.e1; }
  int t = threadIdx.x, w = t >> 6;
  int r = t & 15, g = (t >> 4) & 3;

  if (sg.sm){
    // deep-MLP vector stage; swizzled scatter (write conflicts 16-way -> 4-way)
    const ushort* src = sg.sm + (size_t)(sg.cs0 + u)*NN*64;
    int nb = t >> 3, b0 = (t & 7)*8;
    int swz = (t & 3) << 3;                // ((b0+i)>>3)&3 == t&3
    const short8v vz = {0,0,0,0,0,0,0,0};
    short8v v[11];
    #pragma unroll
    for (int j = 0; j < 11; ++j){
      int n = j*32 + nb;
      v[j] = (n < NN) ? *(const short8v*)&src[(size_t)n*64 + b0] : vz;
    }
    #pragma unroll
    for (int j = 0; j < 11; ++j){
      int col = (j*32 + nb) ^ swz;
      #pragma unroll
      for (int i = 0; i < 8; ++i) X[b0 + i][col] = (ushort)v[j][i];
    }
  } else {
    // fp32 x channel: scalar loads + slot-0 writeback; swizzled LDS writes
    for (int j = 0; j < 22; ++j){
      int idx = j*256 + t;                 // 5632 = 64 b * 88 n4-groups
      int b = idx / 88, n4 = (idx - b*88)*4;
      int swz = ((b >> 3) & 3) << 3;
      ushort us[4];
      #pragma unroll
      for (int i = 0; i < 4; ++i)
        us[i] = (n4 + i < NN) ? f2bf(sg.sf[(size_t)b*NN + n4 + i]) : (ushort)0;
      short4v pk; pk[0]=(short)us[0]; pk[1]=(short)us[1]; pk[2]=(short)us[2]; pk[3]=(short)us[3];
      *(short4v*)&X[b][n4 ^ swz] = pk;
      #pragma unroll
      for (int i = 0; i < 4; ++i)
        if (n4 + i < NN) sg.dm[(size_t)(n4 + i)*64 + b] = us[i];
    }
  }
  __syncthreads();

  const ushort* S = da.Sc + ((size_t)m*NPADR + (size_t)y*192)*KD;
  int swr[4];
  #pragma unroll
  for (int nt = 0; nt < 4; ++nt)
    swr[nt] = ((nt*2 + (r >> 3)) & 3) << 3;   // ((nt*16+r)>>3)&3
  float4v acc[3][4];
  #pragma unroll
  for (int i = 0; i < 3; ++i)
    #pragma unroll
    for (int q = 0; q < 4; ++q) acc[i][q] = (float4v){0.f,0.f,0.f,0.f};
  for (int kc = 0; kc < KD/32; ++kc){
    short8v a[3], bbv[4];
    #pragma unroll
    for (int mt = 0; mt < 3; ++mt)
      a[mt] = *(const short8v*)&S[(size_t)((w*3 + mt)*16 + r)*KD + kc*32 + g*8];
    #pragma unroll
    for (int nt = 0; nt < 4; ++nt)
      bbv[nt] = *(const short8v*)&X[nt*16 + r][(kc*32 + g*8) ^ swr[nt]];
    #pragma unroll
    for (int mt = 0; mt < 3; ++mt)
      #pragma unroll
      for (int nt = 0; nt < 4; ++nt)
        acc[mt][nt] = __builtin_amdgcn_mfma_f32_16x16x32_bf16(a[mt], bbv[nt], acc[mt][nt], 0, 0, 0);
  }

  __syncthreads();                        // all waves done reading X -> reuse as OB
  #pragma unroll
  for (int mt = 0; mt < 3; ++mt){
    int lr0 = (w*3 + mt)*16 + g*4;        // local row (within 192-row half)
    #pragma unroll
    for (int nt = 0; nt < 4; ++nt){
      int col = nt*16 + r;
      #pragma unroll
      for (int i = 0; i < 4; ++i)
        OB[lr0 + i][col] = f2bf(acc[mt][nt][i]);
    }
  }
  __syncthreads();
  // coalesced copy-out: full 128B lines (8 lanes x 16B per row)
  {
    ushort* dst = sg.dm + (size_t)((1 + m)*sg.C + sg.cd0 + u)*NN*64;
    int n0 = y*192;
    int lr = t >> 3, q = (t & 7)*8;
    #pragma unroll
    for (int it = 0; it < 6; ++it){
      int row = it*32 + lr;
      int n = n0 + row;
      if (n < NN)
        *(short8v*)&dst[(size_t)n*64 + q] = *(short8v*)&OB[row][q];
    }
  }
}

// ------------------------------------------- dual-descriptor W-GEMM (MFMA) ----
struct WgD {
  const ushort* mats; const ushort* Wt; const float* bias;
  float* h; float* uu;
  ushort* dstA; ushort* dstB;         // kk-major slot bases (dstB may be null)
  const float* Wfc; const float* bfc; float* outp;
  const float* xnext; ushort* xdst;   // optional next-x stage (MODE 1)
  int KPAD; int MODE;      // MODE 0: gate (o-tile = oy*64); 1: cand (h-update)
};

template<int KPAD>
static __device__ __forceinline__ void wg_body(
    const WgD& d, int n, int oy, ushort (*XT)[XP], float* fcbuf)
{
  constexpr int NST = (KPAD > 352) ? 2 : 1;
  constexpr int KH  = (KPAD > 352) ? 320 : KPAD;
  constexpr int NCH = KH/32;
  int t = threadIdx.x, w = t >> 6;
  int r = t & 15, g = (t >> 4) & 3;
  const bool fc = (d.MODE == 1) && (d.outp != nullptr);
  if (fc && t < 64) fcbuf[t] = 0.f;

  float4v acc[4];
  #pragma unroll
  for (int nt = 0; nt < 4; ++nt) acc[nt] = (float4v){0.f,0.f,0.f,0.f};

  int kk0 = t >> 3, b0 = (t & 7)*8;
  int swz = (t & 3) << 3;
  int swr[4];
  #pragma unroll
  for (int nt = 0; nt < 4; ++nt)
    swr[nt] = ((nt*2 + (r >> 3)) & 3) << 3;
  #pragma unroll
  for (int st = 0; st < NST; ++st){
    int kbase = st*KH;
    if (st) __syncthreads();
    short8v v[NCH];
    #pragma unroll
    for (int j = 0; j < NCH; ++j)
      v[j] = *(const short8v*)&d.mats[((size_t)(kbase + j*32 + kk0)*NN + n)*64 + b0];
    #pragma unroll
    for (int j = 0; j < NCH; ++j){
      int col = (j*32 + kk0) ^ swz;
      #pragma unroll
      for (int i = 0; i < 8; ++i) XT[b0 + i][col] = (ushort)v[j][i];
    }
    __syncthreads();
    for (int kc = 0; kc < NCH; ++kc){
      short8v a0 = *(const short8v*)&d.Wt[(size_t)(oy*64 + w*16 + r)*KPAD + kbase + kc*32 + g*8];
      short8v bbv[4];
      #pragma unroll
      for (int nt = 0; nt < 4; ++nt)
        bbv[nt] = *(const short8v*)&XT[nt*16 + r][(kc*32 + g*8) ^ swr[nt]];
      #pragma unroll
      for (int nt = 0; nt < 4; ++nt)
        acc[nt] = __builtin_amdgcn_mfma_f32_16x16x32_bf16(a0, bbv[nt], acc[nt], 0, 0, 0);
    }
  }

  __syncthreads();                        // all XT reads done; reuse as out stage
  #pragma unroll
  for (int nt = 0; nt < 4; ++nt){
    int b2 = nt*16 + r;
    float p = 0.f;
    #pragma unroll
    for (int i = 0; i < 4; ++i){
      int o = w*16 + g*4 + i;             // within o-tile
      float vv = acc[nt][i] + d.bias[oy*64 + o];
      if (d.MODE == 0){
        float sg = 1.f/(1.f + expf(-vv));
        if (oy == 0) XT[o][b2] = f2bf(sg * d.h[(size_t)n*NODE + o*64 + b2]);
        else         d.uu[(size_t)n*NODE + o*64 + b2] = sg;
      } else {
        float cv = tanhf(vv);
        size_t idx = (size_t)n*NODE + o*64 + b2;
        float uv = d.uu[idx];
        float hn = uv*d.h[idx] + (1.f - uv)*cv;
        d.h[idx] = hn;
        XT[o][b2] = f2bf(hn);
        if (fc) p += hn * d.Wfc[o];
      }
    }
    if (fc) atomicAdd(&fcbuf[b2], p);
  }
  __syncthreads();
  if (d.MODE == 1 || oy == 0){             // coalesced copy-out of 64 kk-lines
    int o = t >> 2, q = (t & 3)*16;
    short8v v0 = *(short8v*)&XT[o][q];
    short8v v1 = *(short8v*)&XT[o][q + 8];
    ushort* dl = d.dstA + ((size_t)o*NN + n)*64 + q;
    *(short8v*)&dl[0] = v0;
    *(short8v*)&dl[8] = v1;
    if (d.dstB){
      ushort* dl2 = d.dstB + ((size_t)o*NN + n)*64 + q;
      *(short8v*)&dl2[0] = v0;
      *(short8v*)&dl2[8] = v1;
    }
  }
  if (d.MODE == 1){
    if (d.xnext && t < 64)
      d.xdst[(size_t)n*64 + t] = f2bf(d.xnext[(size_t)t*NN + n]);
    if (fc && t < 64)
      d.outp[(size_t)t*NN + n] = fcbuf[t] + d.bfc[0];
  }
}

__global__ __launch_bounds__(256) void k_wg2(WgD d0, int n0, WgD d1){
  __shared__ ushort XT[64][XP];
  __shared__ float fcbuf[64];
  const bool first = (blockIdx.x < (unsigned)n0);
  WgD d = first ? d0 : d1;
  int n = first ? blockIdx.x : blockIdx.x - n0;
  int oy = blockIdx.y;
  if (d.MODE == 1 && oy) return;           // block-uniform early exit
  if (d.KPAD == 352) wg_body<352>(d, n, oy, XT, fcbuf);
  else               wg_body<640>(d, n, oy, XT, fcbuf);
}

// ----------------------------------------------------------------- host ----
extern "C" void kernel_launch(void* const* d_in, const int* in_sizes, int n_in,
                              void* d_out, int out_size, void* d_ws, size_t ws_size,
                              hipStream_t stream){
  const float* inp  = (const float*)d_in[0];
  const float* init = (const float*)d_in[1];
  const float* adj  = (const float*)d_in[2];
  const float* Wg0  = (const float*)d_in[3];
  const float* bg0  = (const float*)d_in[4];
  const float* Wc0  = (const float*)d_in[5];
  const float* bc0  = (const float*)d_in[6];
  const float* Wg1  = (const float*)d_in[7];
  const float* bg1  = (const float*)d_in[8];
  const float* Wc1  = (const float*)d_in[9];
  const float* bc1  = (const float*)d_in[10];
  const float* Wfc  = (const float*)d_in[11];
  const float* bfc  = (const float*)d_in[12];
  (void)in_sizes; (void)n_in; (void)out_size; (void)ws_size;

  char* p = (char*)d_ws;
  auto alloc = [&](size_t bytes) -> void* {
    void* q = (void*)p; p += (bytes + 255) & ~(size_t)255; return q;
  };
  ushort* Scomb  = (ushort*)alloc((size_t)4*NPADR*KD*2);
  float*  Sfp    = (float*)alloc((size_t)2*NN*NN*4);
  ushort* Wg0t   = (ushort*)alloc((size_t)128*KP0*2);
  ushort* Wc0t   = (ushort*)alloc((size_t)64*KP0*2);
  ushort* Wg1t   = (ushort*)alloc((size_t)128*KP1*2);
  ushort* Wc1t   = (ushort*)alloc((size_t)64*KP1*2);
  float*  rs     = (float*)alloc(512*4);
  float*  cs     = (float*)alloc(512*4);
  float*  h0     = (float*)alloc((size_t)NN*NODE*4);
  float*  h1     = (float*)alloc((size_t)NN*NODE*4);
  float*  uu0    = (float*)alloc((size_t)NN*NODE*4);
  float*  uu1    = (float*)alloc((size_t)NN*NODE*4);
  ushort* matsL0 = (ushort*)alloc((size_t)KP0*NN*64*2);
  ushort* matsL1 = (ushort*)alloc((size_t)KP1*NN*64*2);
  float* out = (float*)d_out;

  hipMemsetAsync(out, 0, (size_t)BB*NN*4, stream);
  hipMemsetAsync(matsL0 + (size_t)325*NN*64, 0, (size_t)(KP0 - 325)*NN*64*2, stream);
  hipMemsetAsync(Scomb, 0, (size_t)4*NPADR*KD*2, stream);

  k_sums<<<NN, 256, 0, stream>>>(adj, rs, cs);
  k_setup2<<<SB2, 256, 0, stream>>>(adj, rs, cs, inp, init, Wg0, Wc0, Wg1, Wc1,
                                    Sfp, Scomb, Wg0t, Wc0t, Wg1t, Wc1t,
                                    h0, h1, matsL0, matsL1);
  k_s2<<<dim3(6, 2, 2), 256, 0, stream>>>(Sfp, Scomb);

  Seg segL0g  = { matsL0, nullptr, matsL0, 65, 0, 0 };      // full gate L0 (65 ch)
  Seg segL0c  = { matsL0, nullptr, matsL0, 65, 1, 1 };      // rh / h0 (64 ch)
  Seg segL1h1 = { matsL1, nullptr, matsL1, 128, 64, 64 };   // h1 / rh1 (64 ch)
  Seg segL1h0 = { matsL1, nullptr, matsL1, 128, 0, 0 };     // h0-part (64 ch)

  auto diffGrid = [](int nch){ return ((nch + 7)/8)*64; };

  // priming: full L0-gate diffusion (x_0 + h0)
  { DiffA da = { Scomb, { segL0g, segL0g, segL0g }, 65, 65, 65 };
    k_diffN<<<diffGrid(65), 256, 0, stream>>>(da); }

  WgD wg_g0 = { matsL0, Wg0t, bg0, h0, uu0, matsL0 + (size_t)1*NN*64, nullptr,
                nullptr, nullptr, nullptr, nullptr, nullptr, KP0, 0 };
  WgD wg_c0 = { matsL0, Wc0t, bc0, h0, uu0, matsL0 + (size_t)1*NN*64, matsL1,
                nullptr, nullptr, nullptr, nullptr, nullptr, KP0, 1 };
  WgD wg_g1 = { matsL1, Wg1t, bg1, h1, uu1, matsL1 + (size_t)64*NN*64, nullptr,
                nullptr, nullptr, nullptr, nullptr, nullptr, KP1, 0 };

  k_wg2<<<dim3(NN, 2), 256, 0, stream>>>(wg_g0, NN, wg_g0);   // wg L0-gate, t=0

  for (int t = 0; t < TT; ++t){
    // P2: L0-cand diff (rh) + L1-gate diff h1-part
    { DiffA da = { Scomb, { segL0c, segL1h1, segL0c }, 64, 128, 128 };
      k_diffN<<<diffGrid(128), 256, 0, stream>>>(da); }
    // P3: wg L0-cand -> h0_new
    k_wg2<<<dim3(NN, 1), 256, 0, stream>>>(wg_c0, NN, wg_c0);
    // P4: L1-gate diff h0-part + next-L0-gate diff h0-part + x_{t+1} channel
    { Seg segX = { nullptr, inp + (size_t)(t + 1)*BB*NN, matsL0, 65, 0, 0 };
      DiffA da = { Scomb, { segL1h0, segL0c, segX }, 64, 128, 129 };
      k_diffN<<<diffGrid(129), 256, 0, stream>>>(da); }
    // P5: wg L1-gate -> rh1 + uu1
    k_wg2<<<dim3(NN, 2), 256, 0, stream>>>(wg_g1, NN, wg_g1);
    // P6: L1-cand diff (rh1)
    { DiffA da = { Scomb, { segL1h1, segL1h1, segL1h1 }, 64, 64, 64 };
      k_diffN<<<diffGrid(64), 256, 0, stream>>>(da); }
    // P7: wg L1-cand (+fc)  [merged with next step's wg L0-gate]
    WgD wg_c1 = { matsL1, Wc1t, bc1, h1, uu1, matsL1 + (size_t)64*NN*64, nullptr,
                  Wfc, bfc, out + (size_t)(t + 1)*BB*NN,
                  (t + 1 < TT) ? inp + (size_t)(t + 1)*BB*NN : nullptr, matsL0,
                  KP1, 1 };
    if (t < TT - 1)
      k_wg2<<<dim3(2*NN, 2), 256, 0, stream>>>(wg_c1, NN, wg_g0);
    else
      k_wg2<<<dim3(NN, 1), 256, 0, stream>>>(wg_c1, NN, wg_c1);
  }
}